// Round 7
// baseline (393.612 us; speedup 1.0000x reference)
//
#include <hip/hip_runtime.h>
#include <hip/hip_bf16.h>
#include <math.h>

// MixerBlock on MI355X — R14: consolidate on the R13-validated 4-wave 8-phase
// 128x128/BK=64 core (2 blocks/CU, swizzled LDS, counted vmcnt): k1 and k2
// now use it too (k1 via K pad 224->256; k2 K=384 -> ntiles=6). R13 proved
// the core at k3: 88us, MfmaUtil 29%, 0 bank conflicts. Old R9 core removed.
// nsplit=4 kept (fine blocks pack the scheduler tail better than 2).
#define B_   64
#define P_   196
#define PPAD 256
#define C_   768
#define TM_  384
#define CM_  3072
#define EPSY 0.1f

typedef unsigned short u16;
typedef __attribute__((ext_vector_type(8))) short bf16x8;
typedef __attribute__((ext_vector_type(4))) float f32x4;

__device__ __forceinline__ float bf2f(u16 v) {
    return __uint_as_float(((unsigned int)v) << 16);
}
__device__ __forceinline__ u16 f2bf(float f) {
    unsigned int u = __float_as_uint(f);
    unsigned int rounding = 0x7FFFu + ((u >> 16) & 1u);
    return (u16)((u + rounding) >> 16);
}

__device__ __forceinline__ void gl_lds16(const u16* g, u16* l) {
    __builtin_amdgcn_global_load_lds(
        (const __attribute__((address_space(1))) unsigned int*)g,
        (__attribute__((address_space(3))) unsigned int*)l,
        16, 0, 0);
}

// ---------------- prep ----------------

__global__ __launch_bounds__(256) void k_prep_xT(const float* __restrict__ x,
                                                 u16* __restrict__ xT,
                                                 float* __restrict__ xn1) {
    __shared__ u16 tile[32][33];
    __shared__ float colsum[32];
    const int b = blockIdx.z, p0 = blockIdx.x * 32, c0 = blockIdx.y * 32;
    const int tx = threadIdx.x & 31, ty = threadIdx.x >> 5;
    if (threadIdx.x < 32) colsum[threadIdx.x] = 0.f;
    const float* xb = x + (size_t)b * P_ * C_;
    float s = 0.f;
    #pragma unroll
    for (int r = 0; r < 4; ++r) {
        int p = p0 + ty + r * 8;
        float v = (p < P_) ? xb[(size_t)p * C_ + c0 + tx] : 0.f;
        u16 h = f2bf(v);
        tile[ty + r * 8][tx] = h;
        float vb = bf2f(h);
        s = fmaf(vb, vb, s);
    }
    __syncthreads();
    u16* dst = xT + ((size_t)b * C_ + c0) * PPAD + p0;
    #pragma unroll
    for (int r = 0; r < 4; ++r) {
        int cl = ty + r * 8;
        dst[(size_t)cl * PPAD + tx] = tile[tx][cl];
    }
    atomicAdd(&colsum[tx], s);
    __syncthreads();
    if (threadIdx.x < 32)
        atomicAdd(&xn1[(size_t)b * C_ + c0 + threadIdx.x], colsum[threadIdx.x]);
}

__device__ __forceinline__ void pad_norm_body(const float* in, u16* outb, float* norm,
                                              int rows, int inlen, int outlen,
                                              int bid, int tid) {
    int wave = (bid * 256 + tid) >> 6;
    int lane = tid & 63;
    if (wave >= rows) return;
    const float* src = in + (size_t)wave * inlen;
    u16* dst = outb + (size_t)wave * outlen;
    float s = 0.f;
    for (int i = lane; i < outlen; i += 64) {
        float v = (i < inlen) ? src[i] : 0.f;
        u16 h = f2bf(v);
        dst[i] = h;
        float vv = bf2f(h);
        s = fmaf(vv, vv, s);
    }
    #pragma unroll
    for (int off = 32; off > 0; off >>= 1) s += __shfl_down(s, off, 64);
    if (lane == 0) norm[wave] = s;
}

__global__ __launch_bounds__(256) void k_prep_weights(
    const float* __restrict__ tw, u16* __restrict__ twb, float* __restrict__ twn,
    const float* __restrict__ cw, u16* __restrict__ cwb, float* __restrict__ cwn,
    const float* __restrict__ w2, u16* __restrict__ w2b,
    const float* __restrict__ w4, u16* __restrict__ w4b) {
    int bid = blockIdx.x, tid = threadIdx.x;
    if (bid < 96) {
        pad_norm_body(tw, twb, twn, TM_, P_, PPAD, bid, tid);
    } else if (bid < 864) {
        pad_norm_body(cw, cwb, cwn, CM_, C_, C_, bid - 96, tid);
    } else if (bid < 1248) {
        int idx = (bid - 864) * 256 + tid;
        int row = idx / TM_;
        w2b[idx] = (row < P_) ? f2bf(w2[(size_t)row * TM_ + (idx % TM_)]) : (u16)0;
    } else {
        int idx = (bid - 1248) * 256 + tid;
        float4 v = ((const float4*)w4)[idx];
        ushort4 o;
        o.x = f2bf(v.x); o.y = f2bf(v.y); o.z = f2bf(v.z); o.w = f2bf(v.w);
        ((ushort4*)w4b)[idx] = o;
    }
}

// ---------------- R13 4-wave 8-phase 128x128 core, BK=64 ----------------
// LDS elems: A [2][128][64] at 0 (16384), B at 16384. 65536 B total.
// Swizzle: LDS[r][c] = G[r][c ^ ((r&7)<<3)]. Units = 64 rows of A or B for
// one K-tile (8KB, 2 gl_lds16/thread). Stage ledger (HW-validated R13):
// {p0,p1: T1.A | p2,p3: N0.B | p4,p5: N0.A | p6,p7: N1.B}, vmcnt(4) at p3/p7.
#define PH_MID()  do { __builtin_amdgcn_sched_barrier(0);                 \
    __builtin_amdgcn_s_barrier();                                         \
    asm volatile("s_waitcnt lgkmcnt(0)" ::: "memory");                    \
    __builtin_amdgcn_sched_barrier(0);                                    \
    __builtin_amdgcn_s_setprio(1); } while (0)
#define PH_END()  do { __builtin_amdgcn_s_setprio(0);                     \
    __builtin_amdgcn_sched_barrier(0);                                    \
    __builtin_amdgcn_s_barrier(); } while (0)
#define PH_END_VM(n) do { __builtin_amdgcn_s_setprio(0);                  \
    asm volatile("s_waitcnt vmcnt(" #n ")" ::: "memory");                 \
    __builtin_amdgcn_sched_barrier(0);                                    \
    __builtin_amdgcn_s_barrier(); } while (0)

#define STG4(isB, d, h, T)                                                \
    do {                                                                  \
        const int ld_ = (isB) ? ldb : lda;                                \
        const u16* g_ = ((isB) ? gB : gA) +                               \
            (size_t)((h) * 64 + srow) * ld_ + (T) * 64 + scol;            \
        u16* s_ = smem + ((isB) ? 16384 : 0) + (d) * 8192 + (h) * 4096 + t * 8; \
        gl_lds16(g_, s_);                                                 \
        gl_lds16(g_ + (size_t)32 * ld_, s_ + 2048);                       \
    } while (0)

#define DSA4(d, mh, Ar)                                                   \
    _Pragma("unroll")                                                     \
    for (int mi = 0; mi < 2; ++mi) {                                      \
        Ar[mi][0] = *(const bf16x8*)(aB0 + (d) * 8192 + ((mh) * 2 + mi) * 1024); \
        Ar[mi][1] = *(const bf16x8*)(aB1 + (d) * 8192 + ((mh) * 2 + mi) * 1024); \
    }
#define DSB4(d, nh, Br)                                                   \
    _Pragma("unroll")                                                     \
    for (int ni = 0; ni < 2; ++ni) {                                      \
        Br[ni][0] = *(const bf16x8*)(bB0 + (d) * 8192 + ((nh) * 2 + ni) * 1024); \
        Br[ni][1] = *(const bf16x8*)(bB1 + (d) * 8192 + ((nh) * 2 + ni) * 1024); \
    }
#define MMQ4(mh, nh, Br)                                                  \
    _Pragma("unroll")                                                     \
    for (int kk = 0; kk < 2; ++kk)                                        \
        _Pragma("unroll")                                                 \
        for (int mi = 0; mi < 2; ++mi)                                    \
            _Pragma("unroll")                                             \
            for (int ni = 0; ni < 2; ++ni)                                \
                acc[(mh) * 2 + mi][(nh) * 2 + ni] =                       \
                    __builtin_amdgcn_mfma_f32_16x16x32_bf16(              \
                        a[mi][kk], Br[ni][kk],                            \
                        acc[(mh) * 2 + mi][(nh) * 2 + ni], 0, 0, 0);

__device__ __forceinline__ void mfma128_8p(
    const u16* __restrict__ gA, const u16* __restrict__ gB,
    int lda, int ldb, int ntiles,
    f32x4 (&acc)[4][4], u16* smem) {
    const int t = threadIdx.x;
    const int w = t >> 6, lane = t & 63;
    const int wr = w >> 1, wc = w & 1;
    const int quad = lane >> 4, l15 = lane & 15;

    // staging: thread t covers elems t*8 and 2048+t*8 of each 64x64 unit
    const int srow = t >> 3;                          // 0..31
    const int scol = (((t & 7) ^ (srow & 7)) << 3);   // pre-swizzled source col

    // reads: swizzled slot addressing
    const int q = (quad * 8) ^ ((l15 & 7) << 3);
    const u16* aB0 = smem + (wr * 64 + l15) * 64 + q;
    const u16* aB1 = smem + (wr * 64 + l15) * 64 + (q ^ 32);
    const u16* bB0 = smem + 16384 + (wc * 64 + l15) * 64 + q;
    const u16* bB1 = smem + 16384 + (wc * 64 + l15) * 64 + (q ^ 32);

    // prologue: T0 {A0,A1,B0,B1} -> buf0 ; T1 {B0,B1} -> buf1 (12 loads)
    STG4(0, 0, 0, 0); STG4(0, 0, 1, 0);
    STG4(1, 0, 0, 0); STG4(1, 0, 1, 0);
    STG4(1, 1, 0, 1); STG4(1, 1, 1, 1);
    asm volatile("s_waitcnt vmcnt(4)" ::: "memory");   // retire T0 (8 loads)
    __builtin_amdgcn_s_barrier();

    bf16x8 a[2][2], b[2][2], c[2][2];
    const int NI = ntiles >> 1;
    for (int i = 0; i < NI - 1; ++i) {
        const int T1 = 2 * i + 1, N0 = 2 * i + 2, N1 = 2 * i + 3;
        // p0
        DSA4(0, 0, a) DSB4(0, 0, b)
        STG4(0, 1, 0, T1);
        PH_MID(); MMQ4(0, 0, b) PH_END();
        // p1
        DSB4(0, 1, c)
        STG4(0, 1, 1, T1);
        PH_MID(); MMQ4(0, 1, c) PH_END();
        // p2
        DSA4(0, 1, a)
        STG4(1, 0, 0, N0);
        PH_MID(); MMQ4(1, 1, c) PH_END();
        // p3
        STG4(1, 0, 1, N0);
        PH_MID(); MMQ4(1, 0, b) PH_END_VM(4);
        // p4
        DSA4(1, 0, a) DSB4(1, 0, b)
        STG4(0, 0, 0, N0);
        PH_MID(); MMQ4(0, 0, b) PH_END();
        // p5
        DSB4(1, 1, c)
        STG4(0, 0, 1, N0);
        PH_MID(); MMQ4(0, 1, c) PH_END();
        // p6
        DSA4(1, 1, a)
        STG4(1, 1, 0, N1);
        PH_MID(); MMQ4(1, 1, c) PH_END();
        // p7
        STG4(1, 1, 1, N1);
        PH_MID(); MMQ4(1, 0, b) PH_END_VM(4);
    }
    // tail: buf0 = tile ntiles-2, buf1 = tile ntiles-1; stage only buf1.A
    {
        const int Tl = ntiles - 1;
        DSA4(0, 0, a) DSB4(0, 0, b)
        STG4(0, 1, 0, Tl);
        PH_MID(); MMQ4(0, 0, b) PH_END();
        DSB4(0, 1, c)
        STG4(0, 1, 1, Tl);
        PH_MID(); MMQ4(0, 1, c) PH_END();
        DSA4(0, 1, a)
        PH_MID(); MMQ4(1, 1, c) PH_END();
        PH_MID(); MMQ4(1, 0, b) PH_END_VM(0);
        DSA4(1, 0, a) DSB4(1, 0, b)
        PH_MID(); MMQ4(0, 0, b) PH_END();
        DSB4(1, 1, c)
        PH_MID(); MMQ4(0, 1, c) PH_END();
        DSA4(1, 1, a)
        PH_MID(); MMQ4(1, 1, c) PH_END();
        PH_MID(); MMQ4(1, 0, b)
        __builtin_amdgcn_s_setprio(0);
    }
}

#define CORE_PRE()                                                        \
    __shared__ __align__(16) u16 smem[32768];                             \
    const int t = threadIdx.x;                                            \
    const int w = t >> 6, l = t & 63;                                     \
    const int wr = w >> 1, wc = w & 1;                                    \
    const int quad = l >> 4, l15 = l & 15;                                \
    f32x4 acc[4][4];                                                      \
    _Pragma("unroll")                                                     \
    for (int m = 0; m < 4; ++m)                                           \
        _Pragma("unroll")                                                 \
        for (int n = 0; n < 4; ++n) acc[m][n] = (f32x4){0.f,0.f,0.f,0.f};

// k1: h1[(b*C+c)][t] = yat(xT, twb); M=49152 N=384 K=256(pad). 8p core.
// grid (8,48,3): m-tile = x + y*8 (XCD stripe), n-tile = z.
__global__ __launch_bounds__(256) void k1_token_yat(
    const u16* __restrict__ xT, const u16* __restrict__ twb,
    const float* __restrict__ tb, const float* __restrict__ twn,
    const float* __restrict__ xn1, const float* __restrict__ alpha, float sb,
    u16* __restrict__ h1) {
    CORE_PRE()
    const int m0 = (blockIdx.x + blockIdx.y * 8) * 128;
    const int n0 = blockIdx.z * 128;
    mfma128_8p(xT + (size_t)m0 * PPAD, twb + (size_t)n0 * PPAD,
               PPAD, PPAD, PPAD / 64, acc, smem);
    const int rbase = m0 + wr * 64;
    const int cbase = n0 + wc * 64;
    float scale = powf(sqrtf(sb), alpha[0]);
    #pragma unroll
    for (int m = 0; m < 4; ++m) {
        #pragma unroll
        for (int n = 0; n < 4; ++n) {
            int col = cbase + n * 16 + l15;
            float bn = tb[col], wnn = twn[col];
            #pragma unroll
            for (int reg = 0; reg < 4; ++reg) {
                int row = rbase + m * 16 + quad * 4 + reg;
                float dnb = acc[m][n][reg];
                float dot = dnb + bn;
                float dist = wnn + xn1[row] - 2.f * dnb;
                h1[(size_t)row * TM_ + col] = f2bf(scale * dot * dot / (dist + EPSY));
            }
        }
    }
}

// k2: x1b = bf16(x + w2 . h1[b]^T + b2); fused xn2 row-norm atomics. 8p core.
// grid (2, 6, 64): m0 = x*128 (rows of w2b, valid < 196), n0 = y*128, b = z.
__global__ __launch_bounds__(256) void k2_token_out(
    const u16* __restrict__ w2b, const u16* __restrict__ h1,
    const float* __restrict__ b2, const float* __restrict__ x,
    float* __restrict__ xn2, u16* __restrict__ x1b) {
    CORE_PRE()
    const int m0 = blockIdx.x * 128, n0 = blockIdx.y * 128;
    const u16* Bz = h1 + (size_t)blockIdx.z * C_ * TM_;
    mfma128_8p(w2b + (size_t)m0 * TM_, Bz + (size_t)n0 * TM_,
               TM_, TM_, TM_ / 64, acc, smem);
    const int rbase = m0 + wr * 64;
    const int cbase = n0 + wc * 64;
    const float* rz = x + (size_t)blockIdx.z * P_ * C_;
    u16* oz = x1b + (size_t)blockIdx.z * P_ * C_;
    float* xrow = xn2 + (size_t)blockIdx.z * P_;
    #pragma unroll
    for (int m = 0; m < 4; ++m) {
        #pragma unroll
        for (int reg = 0; reg < 4; ++reg) {
            int row = rbase + m * 16 + quad * 4 + reg;
            if (row < P_) {
                float bm = b2[row];
                float s = 0.f;
                #pragma unroll
                for (int n = 0; n < 4; ++n) {
                    int col = cbase + n * 16 + l15;
                    float v = acc[m][n][reg] + bm + rz[(size_t)row * C_ + col];
                    u16 h = f2bf(v);
                    oz[(size_t)row * C_ + col] = h;
                    float vb = bf2f(h);
                    s = fmaf(vb, vb, s);
                }
                s += __shfl_xor(s, 1, 64);
                s += __shfl_xor(s, 2, 64);
                s += __shfl_xor(s, 4, 64);
                s += __shfl_xor(s, 8, 64);
                if (l15 == 0) atomicAdd(&xrow[row], s);
            }
        }
    }
}

// k3: h3 = yat(x1b, cwb); M=12544 N=3072 K=768. 8p core.
// grid (8,13,24): mt = x + y*8 (XCD stripe, guard <98), n-tile = z.
__global__ __launch_bounds__(256) void k3_chan_yat(
    const u16* __restrict__ x1b, const u16* __restrict__ cwb,
    const float* __restrict__ cb, const float* __restrict__ cwn,
    const float* __restrict__ xn2, const float* __restrict__ alpha, float sb,
    u16* __restrict__ h3) {
    CORE_PRE()
    const int mt = blockIdx.x + blockIdx.y * 8;
    if (mt >= (B_ * P_) / 128) return;
    const int m0 = mt * 128;
    const int n0 = blockIdx.z * 128;
    mfma128_8p(x1b + (size_t)m0 * C_, cwb + (size_t)n0 * C_,
               C_, C_, C_ / 64, acc, smem);
    const int rbase = m0 + wr * 64;
    const int cbase = n0 + wc * 64;
    float scale = powf(sqrtf(sb), alpha[0]);
    #pragma unroll
    for (int m = 0; m < 4; ++m) {
        #pragma unroll
        for (int n = 0; n < 4; ++n) {
            int col = cbase + n * 16 + l15;
            float bn = cb[col], wnn = cwn[col];
            #pragma unroll
            for (int reg = 0; reg < 4; ++reg) {
                int row = rbase + m * 16 + quad * 4 + reg;
                float dnb = acc[m][n][reg];
                float dot = dnb + bn;
                float dist = wnn + xn2[row] - 2.f * dnb;
                h3[(size_t)row * CM_ + col] = f2bf(scale * dot * dot / (dist + EPSY));
            }
        }
    }
}

// k4 split-K on the 8p core: grid (8,13,6*nsplit):
// mt = x + y*8 (guard <98), n0 = (z%6)*128, ks = z/6.
__global__ __launch_bounds__(256) void k4_split(
    const u16* __restrict__ h3, const u16* __restrict__ w4b,
    u16* __restrict__ pbuf, int KK) {
    CORE_PRE()
    const int mt = blockIdx.x + blockIdx.y * 8;
    if (mt >= (B_ * P_) / 128) return;
    const int m0 = mt * 128;
    const int nz = blockIdx.z;
    const int n0 = (nz % (C_ / 128)) * 128;
    const int ks = nz / (C_ / 128);
    const int kbase = ks * KK;
    mfma128_8p(h3 + (size_t)m0 * CM_ + kbase, w4b + (size_t)n0 * CM_ + kbase,
               CM_, CM_, KK / 64, acc, smem);
    const int rbase = m0 + wr * 64;
    const int cbase = n0 + wc * 64;
    u16* dst = pbuf + (size_t)ks * ((size_t)B_ * P_ * C_);
    #pragma unroll
    for (int m = 0; m < 4; ++m) {
        #pragma unroll
        for (int n = 0; n < 4; ++n) {
            int col = cbase + n * 16 + l15;
            #pragma unroll
            for (int reg = 0; reg < 4; ++reg) {
                int row = rbase + m * 16 + quad * 4 + reg;
                dst[(size_t)row * C_ + col] = f2bf(acc[m][n][reg]);
            }
        }
    }
}

// reduce: out = sum(bf16 pbuf[0..NS-1]) + bf2f(x1b) + b4
template <int NS>
__global__ __launch_bounds__(256) void k4_reduce(
    float* __restrict__ outp, const u16* __restrict__ pbuf,
    const u16* __restrict__ x1b, const float* __restrict__ b4) {
    int idx = blockIdx.x * 256 + threadIdx.x;      // < B*P*C/4
    int c = (idx * 4) % C_;
    ushort4 r = ((const ushort4*)x1b)[idx];
    float4 o;
    o.x = bf2f(r.x) + b4[c + 0];
    o.y = bf2f(r.y) + b4[c + 1];
    o.z = bf2f(r.z) + b4[c + 2];
    o.w = bf2f(r.w) + b4[c + 3];
    const size_t stride4 = (size_t)B_ * P_ * C_ / 4;
    #pragma unroll
    for (int s = 0; s < NS; ++s) {
        ushort4 p = ((const ushort4*)pbuf)[idx + s * stride4];
        o.x += bf2f(p.x); o.y += bf2f(p.y); o.z += bf2f(p.z); o.w += bf2f(p.w);
    }
    ((float4*)outp)[idx] = o;
}

// fallback k4 (tiny ws): 128x64 tile BK=32
__global__ __launch_bounds__(256) void gemm_k4_fb(
    const u16* __restrict__ A, const u16* __restrict__ Bmat,
    const float* __restrict__ biasN, const u16* __restrict__ resB,
    float* __restrict__ Fout) {
    __shared__ u16 As[128 * 32];
    __shared__ u16 Bs[64 * 32];
    const int t = threadIdx.x;
    const int wid = t >> 6, lane = t & 63;
    const int quad = lane >> 4, l15 = lane & 15;
    const int m0 = blockIdx.x * 128, n0 = blockIdx.y * 64;
    f32x4 acc[4][2];
    #pragma unroll
    for (int i = 0; i < 4; ++i)
        #pragma unroll
        for (int j = 0; j < 2; ++j) acc[i][j] = (f32x4){0.f, 0.f, 0.f, 0.f};
    const u16* Aw = As + (wid >> 1) * (64 * 32);
    const u16* Bw = Bs + (wid & 1) * (32 * 32);
    const int arow = t >> 2, akc = (t & 3) * 8;
    for (int k0 = 0; k0 < CM_; k0 += 32) {
        gl_lds16(A + (size_t)(m0 + arow) * CM_ + k0 + akc,      As + wid * 512);
        gl_lds16(A + (size_t)(m0 + 64 + arow) * CM_ + k0 + akc, As + 2048 + wid * 512);
        gl_lds16(Bmat + (size_t)(n0 + arow) * CM_ + k0 + akc,   Bs + wid * 512);
        __syncthreads();
        bf16x8 af[4], bfr[2];
        #pragma unroll
        for (int i = 0; i < 4; ++i)
            af[i] = *(const bf16x8*)(Aw + ((i * 16 + l15) * 32 + quad * 8));
        #pragma unroll
        for (int j = 0; j < 2; ++j)
            bfr[j] = *(const bf16x8*)(Bw + ((j * 16 + l15) * 32 + quad * 8));
        #pragma unroll
        for (int i = 0; i < 4; ++i)
            #pragma unroll
            for (int j = 0; j < 2; ++j)
                acc[i][j] = __builtin_amdgcn_mfma_f32_16x16x32_bf16(af[i], bfr[j], acc[i][j], 0, 0, 0);
        __syncthreads();
    }
    const int rbase = m0 + (wid >> 1) * 64;
    const int cbase = n0 + (wid & 1) * 32;
    #pragma unroll
    for (int i = 0; i < 4; ++i) {
        #pragma unroll
        for (int j = 0; j < 2; ++j) {
            int col = cbase + j * 16 + l15;
            float bn = biasN[col];
            #pragma unroll
            for (int reg = 0; reg < 4; ++reg) {
                int row = rbase + i * 16 + quad * 4 + reg;
                float v = acc[i][j][reg] + bn + bf2f(resB[(size_t)row * C_ + col]);
                Fout[(size_t)row * C_ + col] = v;
            }
        }
    }
}

extern "C" void kernel_launch(void* const* d_in, const int* in_sizes, int n_in,
                              void* d_out, int out_size, void* d_ws, size_t ws_size,
                              hipStream_t stream) {
    const float* x  = (const float*)d_in[0];
    const float* tw = (const float*)d_in[1];
    const float* tb = (const float*)d_in[2];
    const float* ta = (const float*)d_in[3];
    const float* w2 = (const float*)d_in[4];
    const float* b2 = (const float*)d_in[5];
    const float* cw = (const float*)d_in[6];
    const float* cb = (const float*)d_in[7];
    const float* ca = (const float*)d_in[8];
    const float* w4 = (const float*)d_in[9];
    const float* b4 = (const float*)d_in[10];
    float* out = (float*)d_out;

    // ---- workspace layout (aliased) ----
    char* ws = (char*)d_ws;
    u16* h1 = (u16*)ws;                                    // B*C*TM (37.7 MB)
    u16* xT = (u16*)(ws + 37748736);                       // (B*C) x 256 (25.2 MB)
    u16* h3 = (u16*)ws;                                    // (B*P) x CM (77 MB)
    size_t off = 77070336;
    u16* x1b = (u16*)(ws + off); off += (size_t)B_ * P_ * C_ * 2;
    u16* twb = (u16*)(ws + off); off += (size_t)TM_ * PPAD * 2;
    u16* w2b = (u16*)(ws + off); off += (size_t)256 * TM_ * 2;
    u16* cwb = (u16*)(ws + off); off += (size_t)CM_ * C_ * 2;
    u16* w4b = (u16*)(ws + off); off += (size_t)C_ * CM_ * 2;
    float* xn1 = (float*)(ws + off); off += (size_t)B_ * C_ * 4;
    float* xn2 = (float*)(ws + off); off += (size_t)B_ * P_ * 4;
    float* twn = (float*)(ws + off); off += (size_t)TM_ * 4;
    float* cwn = (float*)(ws + off); off += (size_t)CM_ * 4;
    u16* pbuf = (u16*)(ws + off);                          // bf16 split-K partials
    const size_t psz = (size_t)B_ * P_ * C_ * 2;           // 19,267,584 per buffer

    int nsplit = 1;
    if (ws_size >= off + 4 * psz)      nsplit = 4;
    else if (ws_size >= off + 2 * psz) nsplit = 2;

    const float SBT = (float)TM_ / logf((float)TM_ + 1.0f);
    const float SBC = (float)CM_ / logf((float)CM_ + 1.0f);

    // ---- prep ----
    hipMemsetAsync(xn1, 0, (size_t)(B_ * C_ + B_ * P_) * 4, stream);
    k_prep_weights<<<3552, 256, 0, stream>>>(tw, twb, twn, cw, cwb, cwn,
                                             w2, w2b, w4, w4b);
    k_prep_xT<<<dim3(PPAD / 32, C_ / 32, B_), 256, 0, stream>>>(x, xT, xn1);

    // ---- k1: M=49152 N=384 K=256(pad) ; 8p core, grid (8,48,3) ----
    k1_token_yat<<<dim3(8, 48, 3), 256, 0, stream>>>(
        xT, twb, tb, twn, xn1, ta, SBT, h1);

    // ---- k2: M=256 N=768 K=384, per-batch ; 8p core ----
    k2_token_out<<<dim3(2, C_ / 128, B_), 256, 0, stream>>>(
        w2b, h1, b2, x, xn2, x1b);

    // ---- k3: M=12544 N=3072 K=768 ; 8p core, grid (8,13,24) ----
    k3_chan_yat<<<dim3(8, 13, 24), 256, 0, stream>>>(
        x1b, cwb, cb, cwn, xn2, ca, SBC, h3);

    // ---- k4: M=12544 N=768 K=3072, split-K bf16 partials, 8p core ----
    if (nsplit > 1) {
        k4_split<<<dim3(8, 13, (C_ / 128) * nsplit), 256, 0, stream>>>(
            h3, w4b, pbuf, CM_ / nsplit);
        int n4 = B_ * P_ * C_ / 4;
        if (nsplit == 4)
            k4_reduce<4><<<(n4 + 255) / 256, 256, 0, stream>>>(out, pbuf, x1b, b4);
        else
            k4_reduce<2><<<(n4 + 255) / 256, 256, 0, stream>>>(out, pbuf, x1b, b4);
    } else {
        gemm_k4_fb<<<dim3(B_ * P_ / 128, C_ / 64), 256, 0, stream>>>(
            h3, w4b, b4, x1b, out);
    }
}

// Round 8
// 373.314 us; speedup vs baseline: 1.0544x; 1.0544x over previous
//
#include <hip/hip_runtime.h>
#include <hip/hip_bf16.h>
#include <math.h>

// MixerBlock on MI355X — R15: revert to the R13 measured-best config (357us).
// R14's port of k1/k2 onto the 8-phase core regressed (−37us): at ntiles=4..6
// the 8p pipeline never reaches steady state (1-2 main iters vs a serialized
// prologue+tail), and k1's K-pad 224->256 added 14% dead FLOPs. Rule learned:
// 8p core for ntiles>=8 (k3, k4_split); R9 2-deep BK=32 core for short-K
// (k1 K=224, k2 K=384). nsplit=4. Swizzled LDS, counted vmcnt, 2 blocks/CU.
#define B_   64
#define P_   196
#define PPAD 224
#define C_   768
#define TM_  384
#define CM_  3072
#define EPSY 0.1f

typedef unsigned short u16;
typedef __attribute__((ext_vector_type(8))) short bf16x8;
typedef __attribute__((ext_vector_type(4))) float f32x4;

__device__ __forceinline__ float bf2f(u16 v) {
    return __uint_as_float(((unsigned int)v) << 16);
}
__device__ __forceinline__ u16 f2bf(float f) {
    unsigned int u = __float_as_uint(f);
    unsigned int rounding = 0x7FFFu + ((u >> 16) & 1u);
    return (u16)((u + rounding) >> 16);
}

__device__ __forceinline__ void gl_lds16(const u16* g, u16* l) {
    __builtin_amdgcn_global_load_lds(
        (const __attribute__((address_space(1))) unsigned int*)g,
        (__attribute__((address_space(3))) unsigned int*)l,
        16, 0, 0);
}

// ---------------- prep ----------------

__global__ __launch_bounds__(256) void k_prep_xT(const float* __restrict__ x,
                                                 u16* __restrict__ xT,
                                                 float* __restrict__ xn1) {
    __shared__ u16 tile[32][33];
    __shared__ float colsum[32];
    const int b = blockIdx.z, p0 = blockIdx.x * 32, c0 = blockIdx.y * 32;
    const int tx = threadIdx.x & 31, ty = threadIdx.x >> 5;
    if (threadIdx.x < 32) colsum[threadIdx.x] = 0.f;
    const float* xb = x + (size_t)b * P_ * C_;
    float s = 0.f;
    #pragma unroll
    for (int r = 0; r < 4; ++r) {
        int p = p0 + ty + r * 8;
        float v = (p < P_) ? xb[(size_t)p * C_ + c0 + tx] : 0.f;
        u16 h = f2bf(v);
        tile[ty + r * 8][tx] = h;
        float vb = bf2f(h);
        s = fmaf(vb, vb, s);
    }
    __syncthreads();
    u16* dst = xT + ((size_t)b * C_ + c0) * PPAD + p0;
    #pragma unroll
    for (int r = 0; r < 4; ++r) {
        int cl = ty + r * 8;
        dst[(size_t)cl * PPAD + tx] = tile[tx][cl];
    }
    atomicAdd(&colsum[tx], s);
    __syncthreads();
    if (threadIdx.x < 32)
        atomicAdd(&xn1[(size_t)b * C_ + c0 + threadIdx.x], colsum[threadIdx.x]);
}

__device__ __forceinline__ void pad_norm_body(const float* in, u16* outb, float* norm,
                                              int rows, int inlen, int outlen,
                                              int bid, int tid) {
    int wave = (bid * 256 + tid) >> 6;
    int lane = tid & 63;
    if (wave >= rows) return;
    const float* src = in + (size_t)wave * inlen;
    u16* dst = outb + (size_t)wave * outlen;
    float s = 0.f;
    for (int i = lane; i < outlen; i += 64) {
        float v = (i < inlen) ? src[i] : 0.f;
        u16 h = f2bf(v);
        dst[i] = h;
        float vv = bf2f(h);
        s = fmaf(vv, vv, s);
    }
    #pragma unroll
    for (int off = 32; off > 0; off >>= 1) s += __shfl_down(s, off, 64);
    if (lane == 0) norm[wave] = s;
}

__global__ __launch_bounds__(256) void k_prep_weights(
    const float* __restrict__ tw, u16* __restrict__ twb, float* __restrict__ twn,
    const float* __restrict__ cw, u16* __restrict__ cwb, float* __restrict__ cwn,
    const float* __restrict__ w2, u16* __restrict__ w2b,
    const float* __restrict__ w4, u16* __restrict__ w4b) {
    int bid = blockIdx.x, tid = threadIdx.x;
    if (bid < 96) {
        pad_norm_body(tw, twb, twn, TM_, P_, PPAD, bid, tid);
    } else if (bid < 864) {
        pad_norm_body(cw, cwb, cwn, CM_, C_, C_, bid - 96, tid);
    } else if (bid < 1248) {
        int idx = (bid - 864) * 256 + tid;
        int row = idx / TM_;
        w2b[idx] = (row < P_) ? f2bf(w2[(size_t)row * TM_ + (idx % TM_)]) : (u16)0;
    } else {
        int idx = (bid - 1248) * 256 + tid;
        float4 v = ((const float4*)w4)[idx];
        ushort4 o;
        o.x = f2bf(v.x); o.y = f2bf(v.y); o.z = f2bf(v.z); o.w = f2bf(v.w);
        ((ushort4*)w4b)[idx] = o;
    }
}

// ---------------- R9 128x128 core (k1/k2: short-K shapes) ----------------
__device__ __forceinline__ void mfma_mainloop(
    const u16* __restrict__ A, const u16* __restrict__ B,
    int lda, int ldb, int kiters,
    f32x4 (&acc)[4][4], u16* As, u16* Bs) {
    const int t = threadIdx.x;
    const int w = t >> 6, l = t & 63;
    const int quad = l >> 4, l15 = l & 15;
    const int row0 = t >> 2, kc = (t & 3) * 8;

    const u16* pa0 = A + (size_t)row0 * lda + kc;
    const u16* pa1 = A + (size_t)(64 + row0) * lda + kc;
    const u16* pb0 = B + (size_t)row0 * ldb + kc;
    const u16* pb1 = B + (size_t)(64 + row0) * ldb + kc;

    u16* ldsA0 = As + w * 512;
    u16* ldsA1 = As + 2048 + w * 512;
    u16* ldsB0 = Bs + w * 512;
    u16* ldsB1 = Bs + 2048 + w * 512;

#define STAGE_(bsel, koff)                          \
    do {                                            \
        const int nb_ = (bsel) * 4096;              \
        gl_lds16(pa0 + (koff), ldsA0 + nb_);        \
        gl_lds16(pa1 + (koff), ldsA1 + nb_);        \
        gl_lds16(pb0 + (koff), ldsB0 + nb_);        \
        gl_lds16(pb1 + (koff), ldsB1 + nb_);        \
    } while (0)

    STAGE_(0, 0);
    if (kiters > 1) {
        STAGE_(1, 32);
        asm volatile("s_waitcnt vmcnt(4)" ::: "memory");
    } else {
        asm volatile("s_waitcnt vmcnt(0)" ::: "memory");
    }
    __builtin_amdgcn_s_barrier();

    int cur = 0;
    int koff = 64;
    for (int it = 0; it < kiters; ++it) {
        const u16* Aw = As + cur * 4096 + (w >> 1) * 2048;
        const u16* Bw = Bs + cur * 4096 + (w & 1) * 2048;
        bf16x8 af[4], bfr[4];
        #pragma unroll
        for (int i = 0; i < 4; ++i)
            af[i] = *(const bf16x8*)(Aw + ((i * 16 + l15) * 32 + quad * 8));
        #pragma unroll
        for (int j = 0; j < 4; ++j)
            bfr[j] = *(const bf16x8*)(Bw + ((j * 16 + l15) * 32 + quad * 8));
        asm volatile("s_waitcnt lgkmcnt(0)" ::: "memory");
        __builtin_amdgcn_sched_barrier(0);
        __builtin_amdgcn_s_barrier();
        const bool more2 = (it + 2 < kiters);
        if (more2) { STAGE_(cur, koff); koff += 32; }
        __builtin_amdgcn_s_setprio(1);
        #pragma unroll
        for (int i = 0; i < 4; ++i)
            #pragma unroll
            for (int j = 0; j < 4; ++j)
                acc[i][j] = __builtin_amdgcn_mfma_f32_16x16x32_bf16(af[i], bfr[j], acc[i][j], 0, 0, 0);
        __builtin_amdgcn_s_setprio(0);
        if (it + 1 < kiters) {
            if (more2) asm volatile("s_waitcnt vmcnt(4)" ::: "memory");
            else       asm volatile("s_waitcnt vmcnt(0)" ::: "memory");
            __builtin_amdgcn_s_barrier();
        }
        cur ^= 1;
    }
#undef STAGE_
}

#define MFMA_CORE(AP, BP, LDA, LDB, KITERS)                              \
    __shared__ u16 As[2 * 128 * 32];                                     \
    __shared__ u16 Bs[2 * 128 * 32];                                     \
    const int t = threadIdx.x;                                           \
    const int wid = t >> 6, lane = t & 63;                               \
    const int quad = lane >> 4, l15 = lane & 15;                         \
    f32x4 acc[4][4];                                                     \
    _Pragma("unroll")                                                    \
    for (int i = 0; i < 4; ++i)                                          \
        _Pragma("unroll")                                                \
        for (int j = 0; j < 4; ++j) acc[i][j] = (f32x4){0.f,0.f,0.f,0.f};\
    mfma_mainloop(AP, BP, LDA, LDB, KITERS, acc, As, Bs);                \
    const int rbase = m0 + (wid >> 1) * 64;                              \
    const int cbase = n0 + (wid & 1) * 64;

// ---------------- R13 4-wave 8-phase 128x128 core, BK=64 (k3/k4) ----------------
// LDS elems: A [2][128][64] at 0 (16384), B at 16384. 65536 B total.
// Swizzle: LDS[r][c] = G[r][c ^ ((r&7)<<3)]. Units = 64 rows of A or B for
// one K-tile (8KB, 2 gl_lds16/thread). Stage ledger (HW-validated R13):
// {p0,p1: T1.A | p2,p3: N0.B | p4,p5: N0.A | p6,p7: N1.B}, vmcnt(4) at p3/p7.
#define PH_MID()  do { __builtin_amdgcn_sched_barrier(0);                 \
    __builtin_amdgcn_s_barrier();                                         \
    asm volatile("s_waitcnt lgkmcnt(0)" ::: "memory");                    \
    __builtin_amdgcn_sched_barrier(0);                                    \
    __builtin_amdgcn_s_setprio(1); } while (0)
#define PH_END()  do { __builtin_amdgcn_s_setprio(0);                     \
    __builtin_amdgcn_sched_barrier(0);                                    \
    __builtin_amdgcn_s_barrier(); } while (0)
#define PH_END_VM(n) do { __builtin_amdgcn_s_setprio(0);                  \
    asm volatile("s_waitcnt vmcnt(" #n ")" ::: "memory");                 \
    __builtin_amdgcn_sched_barrier(0);                                    \
    __builtin_amdgcn_s_barrier(); } while (0)

#define STG4(isB, d, h, T)                                                \
    do {                                                                  \
        const int ld_ = (isB) ? ldb : lda;                                \
        const u16* g_ = ((isB) ? gB : gA) +                               \
            (size_t)((h) * 64 + srow) * ld_ + (T) * 64 + scol;            \
        u16* s_ = smem + ((isB) ? 16384 : 0) + (d) * 8192 + (h) * 4096 + t * 8; \
        gl_lds16(g_, s_);                                                 \
        gl_lds16(g_ + (size_t)32 * ld_, s_ + 2048);                       \
    } while (0)

#define DSA4(d, mh, Ar)                                                   \
    _Pragma("unroll")                                                     \
    for (int mi = 0; mi < 2; ++mi) {                                      \
        Ar[mi][0] = *(const bf16x8*)(aB0 + (d) * 8192 + ((mh) * 2 + mi) * 1024); \
        Ar[mi][1] = *(const bf16x8*)(aB1 + (d) * 8192 + ((mh) * 2 + mi) * 1024); \
    }
#define DSB4(d, nh, Br)                                                   \
    _Pragma("unroll")                                                     \
    for (int ni = 0; ni < 2; ++ni) {                                      \
        Br[ni][0] = *(const bf16x8*)(bB0 + (d) * 8192 + ((nh) * 2 + ni) * 1024); \
        Br[ni][1] = *(const bf16x8*)(bB1 + (d) * 8192 + ((nh) * 2 + ni) * 1024); \
    }
#define MMQ4(mh, nh, Br)                                                  \
    _Pragma("unroll")                                                     \
    for (int kk = 0; kk < 2; ++kk)                                        \
        _Pragma("unroll")                                                 \
        for (int mi = 0; mi < 2; ++mi)                                    \
            _Pragma("unroll")                                             \
            for (int ni = 0; ni < 2; ++ni)                                \
                acc[(mh) * 2 + mi][(nh) * 2 + ni] =                       \
                    __builtin_amdgcn_mfma_f32_16x16x32_bf16(              \
                        a[mi][kk], Br[ni][kk],                            \
                        acc[(mh) * 2 + mi][(nh) * 2 + ni], 0, 0, 0);

__device__ __forceinline__ void mfma128_8p(
    const u16* __restrict__ gA, const u16* __restrict__ gB,
    int lda, int ldb, int ntiles,
    f32x4 (&acc)[4][4], u16* smem) {
    const int t = threadIdx.x;
    const int w = t >> 6, lane = t & 63;
    const int wr = w >> 1, wc = w & 1;
    const int quad = lane >> 4, l15 = lane & 15;

    // staging: thread t covers elems t*8 and 2048+t*8 of each 64x64 unit
    const int srow = t >> 3;                          // 0..31
    const int scol = (((t & 7) ^ (srow & 7)) << 3);   // pre-swizzled source col

    // reads: swizzled slot addressing
    const int q = (quad * 8) ^ ((l15 & 7) << 3);
    const u16* aB0 = smem + (wr * 64 + l15) * 64 + q;
    const u16* aB1 = smem + (wr * 64 + l15) * 64 + (q ^ 32);
    const u16* bB0 = smem + 16384 + (wc * 64 + l15) * 64 + q;
    const u16* bB1 = smem + 16384 + (wc * 64 + l15) * 64 + (q ^ 32);

    // prologue: T0 {A0,A1,B0,B1} -> buf0 ; T1 {B0,B1} -> buf1 (12 loads)
    STG4(0, 0, 0, 0); STG4(0, 0, 1, 0);
    STG4(1, 0, 0, 0); STG4(1, 0, 1, 0);
    STG4(1, 1, 0, 1); STG4(1, 1, 1, 1);
    asm volatile("s_waitcnt vmcnt(4)" ::: "memory");   // retire T0 (8 loads)
    __builtin_amdgcn_s_barrier();

    bf16x8 a[2][2], b[2][2], c[2][2];
    const int NI = ntiles >> 1;
    for (int i = 0; i < NI - 1; ++i) {
        const int T1 = 2 * i + 1, N0 = 2 * i + 2, N1 = 2 * i + 3;
        // p0
        DSA4(0, 0, a) DSB4(0, 0, b)
        STG4(0, 1, 0, T1);
        PH_MID(); MMQ4(0, 0, b) PH_END();
        // p1
        DSB4(0, 1, c)
        STG4(0, 1, 1, T1);
        PH_MID(); MMQ4(0, 1, c) PH_END();
        // p2
        DSA4(0, 1, a)
        STG4(1, 0, 0, N0);
        PH_MID(); MMQ4(1, 1, c) PH_END();
        // p3
        STG4(1, 0, 1, N0);
        PH_MID(); MMQ4(1, 0, b) PH_END_VM(4);
        // p4
        DSA4(1, 0, a) DSB4(1, 0, b)
        STG4(0, 0, 0, N0);
        PH_MID(); MMQ4(0, 0, b) PH_END();
        // p5
        DSB4(1, 1, c)
        STG4(0, 0, 1, N0);
        PH_MID(); MMQ4(0, 1, c) PH_END();
        // p6
        DSA4(1, 1, a)
        STG4(1, 1, 0, N1);
        PH_MID(); MMQ4(1, 1, c) PH_END();
        // p7
        STG4(1, 1, 1, N1);
        PH_MID(); MMQ4(1, 0, b) PH_END_VM(4);
    }
    // tail: buf0 = tile ntiles-2, buf1 = tile ntiles-1; stage only buf1.A
    {
        const int Tl = ntiles - 1;
        DSA4(0, 0, a) DSB4(0, 0, b)
        STG4(0, 1, 0, Tl);
        PH_MID(); MMQ4(0, 0, b) PH_END();
        DSB4(0, 1, c)
        STG4(0, 1, 1, Tl);
        PH_MID(); MMQ4(0, 1, c) PH_END();
        DSA4(0, 1, a)
        PH_MID(); MMQ4(1, 1, c) PH_END();
        PH_MID(); MMQ4(1, 0, b) PH_END_VM(0);
        DSA4(1, 0, a) DSB4(1, 0, b)
        PH_MID(); MMQ4(0, 0, b) PH_END();
        DSB4(1, 1, c)
        PH_MID(); MMQ4(0, 1, c) PH_END();
        DSA4(1, 1, a)
        PH_MID(); MMQ4(1, 1, c) PH_END();
        PH_MID(); MMQ4(1, 0, b)
        __builtin_amdgcn_s_setprio(0);
    }
}

// k1: h1[(b*C+c)][t] = yat(xT, twb); M=49152 N=384 K=224 (R9 core).
__global__ __launch_bounds__(256) void k1_token_yat(
    const u16* __restrict__ xT, const u16* __restrict__ twb,
    const float* __restrict__ tb, const float* __restrict__ twn,
    const float* __restrict__ xn1, const float* __restrict__ alpha, float sb,
    u16* __restrict__ h1) {
    const int m0 = (blockIdx.x + blockIdx.y * 8) * 128;
    const int n0 = blockIdx.z * 128;
    MFMA_CORE(xT + (size_t)m0 * PPAD, twb + (size_t)n0 * PPAD, PPAD, PPAD, PPAD / 32)
    float scale = powf(sqrtf(sb), alpha[0]);
    #pragma unroll
    for (int i = 0; i < 4; ++i) {
        #pragma unroll
        for (int j = 0; j < 4; ++j) {
            int col = cbase + j * 16 + l15;
            float bn = tb[col], wnn = twn[col];
            #pragma unroll
            for (int reg = 0; reg < 4; ++reg) {
                int row = rbase + i * 16 + quad * 4 + reg;
                float dnb = acc[i][j][reg];
                float dot = dnb + bn;
                float dist = wnn + xn1[row] - 2.f * dnb;
                h1[(size_t)row * TM_ + col] = f2bf(scale * dot * dot / (dist + EPSY));
            }
        }
    }
}

// k3: h3 = yat(x1b, cwb); M=12544 N=3072 K=768. 4-wave 8-phase 128² core.
// grid (8,13,24): mt = x + y*8 (XCD stripe, guard <98), n-tile = z.
__global__ __launch_bounds__(256) void k3_chan_yat(
    const u16* __restrict__ x1b, const u16* __restrict__ cwb,
    const float* __restrict__ cb, const float* __restrict__ cwn,
    const float* __restrict__ xn2, const float* __restrict__ alpha, float sb,
    u16* __restrict__ h3) {
    __shared__ __align__(16) u16 smem[32768];
    const int mt = blockIdx.x + blockIdx.y * 8;
    if (mt >= (B_ * P_) / 128) return;
    const int m0 = mt * 128;
    const int n0 = blockIdx.z * 128;
    const int t = threadIdx.x;
    const int w = t >> 6, l = t & 63;
    const int wr = w >> 1, wc = w & 1;
    const int quad = l >> 4, l15 = l & 15;
    f32x4 acc[4][4];
    #pragma unroll
    for (int m = 0; m < 4; ++m)
        #pragma unroll
        for (int n = 0; n < 4; ++n) acc[m][n] = (f32x4){0.f, 0.f, 0.f, 0.f};
    mfma128_8p(x1b + (size_t)m0 * C_, cwb + (size_t)n0 * C_,
               C_, C_, C_ / 64, acc, smem);
    const int rbase = m0 + wr * 64;
    const int cbase = n0 + wc * 64;
    float scale = powf(sqrtf(sb), alpha[0]);
    #pragma unroll
    for (int m = 0; m < 4; ++m) {
        #pragma unroll
        for (int n = 0; n < 4; ++n) {
            int col = cbase + n * 16 + l15;
            float bn = cb[col], wnn = cwn[col];
            #pragma unroll
            for (int reg = 0; reg < 4; ++reg) {
                int row = rbase + m * 16 + quad * 4 + reg;
                float dnb = acc[m][n][reg];
                float dot = dnb + bn;
                float dist = wnn + xn2[row] - 2.f * dnb;
                h3[(size_t)row * CM_ + col] = f2bf(scale * dot * dot / (dist + EPSY));
            }
        }
    }
}

// k2: x1b = bf16(x + w2 . h1[b]^T + b2); fused xn2 row-norm atomics (R9 core).
__global__ __launch_bounds__(256) void k2_token_out(
    const u16* __restrict__ w2b, const u16* __restrict__ h1,
    const float* __restrict__ b2, const float* __restrict__ x,
    float* __restrict__ xn2, u16* __restrict__ x1b) {
    const int m0 = blockIdx.x * 128, n0 = blockIdx.y * 128;
    const u16* Bz = h1 + (size_t)blockIdx.z * C_ * TM_;
    MFMA_CORE(w2b + (size_t)m0 * TM_, Bz + (size_t)n0 * TM_, TM_, TM_, TM_ / 32)
    const float* rz = x + (size_t)blockIdx.z * P_ * C_;
    u16* oz = x1b + (size_t)blockIdx.z * P_ * C_;
    float* xrow = xn2 + (size_t)blockIdx.z * P_;
    #pragma unroll
    for (int i = 0; i < 4; ++i) {
        #pragma unroll
        for (int reg = 0; reg < 4; ++reg) {
            int row = rbase + i * 16 + quad * 4 + reg;
            if (row < P_) {
                float bm = b2[row];
                float s = 0.f;
                #pragma unroll
                for (int j = 0; j < 4; ++j) {
                    int col = cbase + j * 16 + l15;
                    float v = acc[i][j][reg] + bm + rz[(size_t)row * C_ + col];
                    u16 h = f2bf(v);
                    oz[(size_t)row * C_ + col] = h;
                    float vb = bf2f(h);
                    s = fmaf(vb, vb, s);
                }
                s += __shfl_xor(s, 1, 64);
                s += __shfl_xor(s, 2, 64);
                s += __shfl_xor(s, 4, 64);
                s += __shfl_xor(s, 8, 64);
                if (l15 == 0) atomicAdd(&xrow[row], s);
            }
        }
    }
}

// k4 split-K on the 4-wave 128² core: grid (8,13,6*nsplit):
// mt = x + y*8 (guard <98), n0 = (z%6)*128, ks = z/6.
__global__ __launch_bounds__(256) void k4_split(
    const u16* __restrict__ h3, const u16* __restrict__ w4b,
    u16* __restrict__ pbuf, int KK) {
    __shared__ __align__(16) u16 smem[32768];
    const int mt = blockIdx.x + blockIdx.y * 8;
    if (mt >= (B_ * P_) / 128) return;
    const int m0 = mt * 128;
    const int nz = blockIdx.z;
    const int n0 = (nz % (C_ / 128)) * 128;
    const int ks = nz / (C_ / 128);
    const int kbase = ks * KK;
    const int t = threadIdx.x;
    const int w = t >> 6, l = t & 63;
    const int wr = w >> 1, wc = w & 1;
    const int quad = l >> 4, l15 = l & 15;
    f32x4 acc[4][4];
    #pragma unroll
    for (int m = 0; m < 4; ++m)
        #pragma unroll
        for (int n = 0; n < 4; ++n) acc[m][n] = (f32x4){0.f, 0.f, 0.f, 0.f};
    mfma128_8p(h3 + (size_t)m0 * CM_ + kbase, w4b + (size_t)n0 * CM_ + kbase,
               CM_, CM_, KK / 64, acc, smem);
    const int rbase = m0 + wr * 64;
    const int cbase = n0 + wc * 64;
    u16* dst = pbuf + (size_t)ks * ((size_t)B_ * P_ * C_);
    #pragma unroll
    for (int m = 0; m < 4; ++m) {
        #pragma unroll
        for (int n = 0; n < 4; ++n) {
            int col = cbase + n * 16 + l15;
            #pragma unroll
            for (int reg = 0; reg < 4; ++reg) {
                int row = rbase + m * 16 + quad * 4 + reg;
                dst[(size_t)row * C_ + col] = f2bf(acc[m][n][reg]);
            }
        }
    }
}

// reduce: out = sum(bf16 pbuf[0..NS-1]) + bf2f(x1b) + b4
template <int NS>
__global__ __launch_bounds__(256) void k4_reduce(
    float* __restrict__ outp, const u16* __restrict__ pbuf,
    const u16* __restrict__ x1b, const float* __restrict__ b4) {
    int idx = blockIdx.x * 256 + threadIdx.x;      // < B*P*C/4
    int c = (idx * 4) % C_;
    ushort4 r = ((const ushort4*)x1b)[idx];
    float4 o;
    o.x = bf2f(r.x) + b4[c + 0];
    o.y = bf2f(r.y) + b4[c + 1];
    o.z = bf2f(r.z) + b4[c + 2];
    o.w = bf2f(r.w) + b4[c + 3];
    const size_t stride4 = (size_t)B_ * P_ * C_ / 4;
    #pragma unroll
    for (int s = 0; s < NS; ++s) {
        ushort4 p = ((const ushort4*)pbuf)[idx + s * stride4];
        o.x += bf2f(p.x); o.y += bf2f(p.y); o.z += bf2f(p.z); o.w += bf2f(p.w);
    }
    ((float4*)outp)[idx] = o;
}

// fallback k4 (tiny ws): 128x64 tile BK=32
__global__ __launch_bounds__(256) void gemm_k4_fb(
    const u16* __restrict__ A, const u16* __restrict__ Bmat,
    const float* __restrict__ biasN, const u16* __restrict__ resB,
    float* __restrict__ Fout) {
    __shared__ u16 As[128 * 32];
    __shared__ u16 Bs[64 * 32];
    const int t = threadIdx.x;
    const int wid = t >> 6, lane = t & 63;
    const int quad = lane >> 4, l15 = lane & 15;
    const int m0 = blockIdx.x * 128, n0 = blockIdx.y * 64;
    f32x4 acc[4][2];
    #pragma unroll
    for (int i = 0; i < 4; ++i)
        #pragma unroll
        for (int j = 0; j < 2; ++j) acc[i][j] = (f32x4){0.f, 0.f, 0.f, 0.f};
    const u16* Aw = As + (wid >> 1) * (64 * 32);
    const u16* Bw = Bs + (wid & 1) * (32 * 32);
    const int arow = t >> 2, akc = (t & 3) * 8;
    for (int k0 = 0; k0 < CM_; k0 += 32) {
        gl_lds16(A + (size_t)(m0 + arow) * CM_ + k0 + akc,      As + wid * 512);
        gl_lds16(A + (size_t)(m0 + 64 + arow) * CM_ + k0 + akc, As + 2048 + wid * 512);
        gl_lds16(Bmat + (size_t)(n0 + arow) * CM_ + k0 + akc,   Bs + wid * 512);
        __syncthreads();
        bf16x8 af[4], bfr[2];
        #pragma unroll
        for (int i = 0; i < 4; ++i)
            af[i] = *(const bf16x8*)(Aw + ((i * 16 + l15) * 32 + quad * 8));
        #pragma unroll
        for (int j = 0; j < 2; ++j)
            bfr[j] = *(const bf16x8*)(Bw + ((j * 16 + l15) * 32 + quad * 8));
        #pragma unroll
        for (int i = 0; i < 4; ++i)
            #pragma unroll
            for (int j = 0; j < 2; ++j)
                acc[i][j] = __builtin_amdgcn_mfma_f32_16x16x32_bf16(af[i], bfr[j], acc[i][j], 0, 0, 0);
        __syncthreads();
    }
    const int rbase = m0 + (wid >> 1) * 64;
    const int cbase = n0 + (wid & 1) * 32;
    #pragma unroll
    for (int i = 0; i < 4; ++i) {
        #pragma unroll
        for (int j = 0; j < 2; ++j) {
            int col = cbase + j * 16 + l15;
            float bn = biasN[col];
            #pragma unroll
            for (int reg = 0; reg < 4; ++reg) {
                int row = rbase + i * 16 + quad * 4 + reg;
                float v = acc[i][j][reg] + bn + bf2f(resB[(size_t)row * C_ + col]);
                Fout[(size_t)row * C_ + col] = v;
            }
        }
    }
}

extern "C" void kernel_launch(void* const* d_in, const int* in_sizes, int n_in,
                              void* d_out, int out_size, void* d_ws, size_t ws_size,
                              hipStream_t stream) {
    const float* x  = (const float*)d_in[0];
    const float* tw = (const float*)d_in[1];
    const float* tb = (const float*)d_in[2];
    const float* ta = (const float*)d_in[3];
    const float* w2 = (const float*)d_in[4];
    const float* b2 = (const float*)d_in[5];
    const float* cw = (const float*)d_in[6];
    const float* cb = (const float*)d_in[7];
    const float* ca = (const float*)d_in[8];
    const float* w4 = (const float*)d_in[9];
    const float* b4 = (const float*)d_in[10];
    float* out = (float*)d_out;

    // ---- workspace layout (aliased) ----
    char* ws = (char*)d_ws;
    u16* h1 = (u16*)ws;                                    // B*C*TM (37.7 MB)
    u16* xT = (u16*)(ws + 37748736);                       // (B*C) x 224 (22 MB)
    u16* h3 = (u16*)ws;                                    // (B*P) x CM (77 MB)
    size_t off = 77070336;
    u16* x1b = (u16*)(ws + off); off += (size_t)B_ * P_ * C_ * 2;
    u16* twb = (u16*)(ws + off); off += (size_t)TM_ * PPAD * 2;
    u16* w2b = (u16*)(ws + off); off += (size_t)256 * TM_ * 2;
    u16* cwb = (u16*)(ws + off); off += (size_t)CM_ * C_ * 2;
    u16* w4b = (u16*)(ws + off); off += (size_t)C_ * CM_ * 2;
    float* xn1 = (float*)(ws + off); off += (size_t)B_ * C_ * 4;
    float* xn2 = (float*)(ws + off); off += (size_t)B_ * P_ * 4;
    float* twn = (float*)(ws + off); off += (size_t)TM_ * 4;
    float* cwn = (float*)(ws + off); off += (size_t)CM_ * 4;
    u16* pbuf = (u16*)(ws + off);                          // bf16 split-K partials
    const size_t psz = (size_t)B_ * P_ * C_ * 2;           // 19,267,584 per buffer

    int nsplit = 1;
    if (ws_size >= off + 4 * psz)      nsplit = 4;
    else if (ws_size >= off + 2 * psz) nsplit = 2;

    const float SBT = (float)TM_ / logf((float)TM_ + 1.0f);
    const float SBC = (float)CM_ / logf((float)CM_ + 1.0f);

    // ---- prep ----
    hipMemsetAsync(xn1, 0, (size_t)(B_ * C_ + B_ * P_) * 4, stream);
    k_prep_weights<<<3552, 256, 0, stream>>>(tw, twb, twn, cw, cwb, cwn,
                                             w2, w2b, w4, w4b);
    k_prep_xT<<<dim3(PPAD / 32, C_ / 32, B_), 256, 0, stream>>>(x, xT, xn1);

    // ---- k1: M=49152 N=384 K=224 ; R9 core, XCD-swizzled grid (8,48,3) ----
    k1_token_yat<<<dim3(8, 48, 3), 256, 0, stream>>>(
        xT, twb, tb, twn, xn1, ta, SBT, h1);

    // ---- k2: M=256 N=768 K=384, per-batch ; R9 core ----
    k2_token_out<<<dim3(2, C_ / 128, B_), 256, 0, stream>>>(
        w2b, h1, b2, x, xn2, x1b);

    // ---- k3: M=12544 N=3072 K=768 ; 4-wave 128² 8-phase, grid (8,13,24) ----
    k3_chan_yat<<<dim3(8, 13, 24), 256, 0, stream>>>(
        x1b, cwb, cb, cwn, xn2, ca, SBC, h3);

    // ---- k4: M=12544 N=768 K=3072, split-K bf16 partials, 8p core ----
    if (nsplit > 1) {
        k4_split<<<dim3(8, 13, (C_ / 128) * nsplit), 256, 0, stream>>>(
            h3, w4b, pbuf, CM_ / nsplit);
        int n4 = B_ * P_ * C_ / 4;
        if (nsplit == 4)
            k4_reduce<4><<<(n4 + 255) / 256, 256, 0, stream>>>(out, pbuf, x1b, b4);
        else
            k4_reduce<2><<<(n4 + 255) / 256, 256, 0, stream>>>(out, pbuf, x1b, b4);
    } else {
        gemm_k4_fb<<<dim3(B_ * P_ / 128, C_ / 64), 256, 0, stream>>>(
            h3, w4b, b4, x1b, out);
    }
}

// Round 9
// 367.101 us; speedup vs baseline: 1.0722x; 1.0169x over previous
//
#include <hip/hip_runtime.h>
#include <hip/hip_bf16.h>
#include <math.h>

// MixerBlock on MI355X — R16: R13/R15 config + two strength reductions inside
// the validated structure (no schedule changes): (1) cursor-based staging in
// mfma128_8p — the 4 staging units advance monotonically (+64 elems/stage,
// verified vs the R13 ledger), so 4 pointer increments replace all per-STG4
// 64-bit address math (VALUBusy was 42% vs MfmaUtil 28%); (2) v_rcp_f32 for
// the yat 1/(dist+eps) (<=1 ULP fp32; invisible in bf16; absmax slack 3.5x).
// Cores: 8p 128²/BK=64 for k3/k4 (ntiles>=12); R9 2-deep BK=32 for k1/k2.
#define B_   64
#define P_   196
#define PPAD 224
#define C_   768
#define TM_  384
#define CM_  3072
#define EPSY 0.1f

typedef unsigned short u16;
typedef __attribute__((ext_vector_type(8))) short bf16x8;
typedef __attribute__((ext_vector_type(4))) float f32x4;

__device__ __forceinline__ float bf2f(u16 v) {
    return __uint_as_float(((unsigned int)v) << 16);
}
__device__ __forceinline__ u16 f2bf(float f) {
    unsigned int u = __float_as_uint(f);
    unsigned int rounding = 0x7FFFu + ((u >> 16) & 1u);
    return (u16)((u + rounding) >> 16);
}

__device__ __forceinline__ void gl_lds16(const u16* g, u16* l) {
    __builtin_amdgcn_global_load_lds(
        (const __attribute__((address_space(1))) unsigned int*)g,
        (__attribute__((address_space(3))) unsigned int*)l,
        16, 0, 0);
}

// ---------------- prep ----------------

__global__ __launch_bounds__(256) void k_prep_xT(const float* __restrict__ x,
                                                 u16* __restrict__ xT,
                                                 float* __restrict__ xn1) {
    __shared__ u16 tile[32][33];
    __shared__ float colsum[32];
    const int b = blockIdx.z, p0 = blockIdx.x * 32, c0 = blockIdx.y * 32;
    const int tx = threadIdx.x & 31, ty = threadIdx.x >> 5;
    if (threadIdx.x < 32) colsum[threadIdx.x] = 0.f;
    const float* xb = x + (size_t)b * P_ * C_;
    float s = 0.f;
    #pragma unroll
    for (int r = 0; r < 4; ++r) {
        int p = p0 + ty + r * 8;
        float v = (p < P_) ? xb[(size_t)p * C_ + c0 + tx] : 0.f;
        u16 h = f2bf(v);
        tile[ty + r * 8][tx] = h;
        float vb = bf2f(h);
        s = fmaf(vb, vb, s);
    }
    __syncthreads();
    u16* dst = xT + ((size_t)b * C_ + c0) * PPAD + p0;
    #pragma unroll
    for (int r = 0; r < 4; ++r) {
        int cl = ty + r * 8;
        dst[(size_t)cl * PPAD + tx] = tile[tx][cl];
    }
    atomicAdd(&colsum[tx], s);
    __syncthreads();
    if (threadIdx.x < 32)
        atomicAdd(&xn1[(size_t)b * C_ + c0 + threadIdx.x], colsum[threadIdx.x]);
}

__device__ __forceinline__ void pad_norm_body(const float* in, u16* outb, float* norm,
                                              int rows, int inlen, int outlen,
                                              int bid, int tid) {
    int wave = (bid * 256 + tid) >> 6;
    int lane = tid & 63;
    if (wave >= rows) return;
    const float* src = in + (size_t)wave * inlen;
    u16* dst = outb + (size_t)wave * outlen;
    float s = 0.f;
    for (int i = lane; i < outlen; i += 64) {
        float v = (i < inlen) ? src[i] : 0.f;
        u16 h = f2bf(v);
        dst[i] = h;
        float vv = bf2f(h);
        s = fmaf(vv, vv, s);
    }
    #pragma unroll
    for (int off = 32; off > 0; off >>= 1) s += __shfl_down(s, off, 64);
    if (lane == 0) norm[wave] = s;
}

__global__ __launch_bounds__(256) void k_prep_weights(
    const float* __restrict__ tw, u16* __restrict__ twb, float* __restrict__ twn,
    const float* __restrict__ cw, u16* __restrict__ cwb, float* __restrict__ cwn,
    const float* __restrict__ w2, u16* __restrict__ w2b,
    const float* __restrict__ w4, u16* __restrict__ w4b) {
    int bid = blockIdx.x, tid = threadIdx.x;
    if (bid < 96) {
        pad_norm_body(tw, twb, twn, TM_, P_, PPAD, bid, tid);
    } else if (bid < 864) {
        pad_norm_body(cw, cwb, cwn, CM_, C_, C_, bid - 96, tid);
    } else if (bid < 1248) {
        int idx = (bid - 864) * 256 + tid;
        int row = idx / TM_;
        w2b[idx] = (row < P_) ? f2bf(w2[(size_t)row * TM_ + (idx % TM_)]) : (u16)0;
    } else {
        int idx = (bid - 1248) * 256 + tid;
        float4 v = ((const float4*)w4)[idx];
        ushort4 o;
        o.x = f2bf(v.x); o.y = f2bf(v.y); o.z = f2bf(v.z); o.w = f2bf(v.w);
        ((ushort4*)w4b)[idx] = o;
    }
}

// ---------------- R9 128x128 core (k1/k2: short-K shapes) ----------------
__device__ __forceinline__ void mfma_mainloop(
    const u16* __restrict__ A, const u16* __restrict__ B,
    int lda, int ldb, int kiters,
    f32x4 (&acc)[4][4], u16* As, u16* Bs) {
    const int t = threadIdx.x;
    const int w = t >> 6, l = t & 63;
    const int quad = l >> 4, l15 = l & 15;
    const int row0 = t >> 2, kc = (t & 3) * 8;

    const u16* pa0 = A + (size_t)row0 * lda + kc;
    const u16* pa1 = A + (size_t)(64 + row0) * lda + kc;
    const u16* pb0 = B + (size_t)row0 * ldb + kc;
    const u16* pb1 = B + (size_t)(64 + row0) * ldb + kc;

    u16* ldsA0 = As + w * 512;
    u16* ldsA1 = As + 2048 + w * 512;
    u16* ldsB0 = Bs + w * 512;
    u16* ldsB1 = Bs + 2048 + w * 512;

#define STAGE_(bsel)                                \
    do {                                            \
        const int nb_ = (bsel) * 4096;              \
        gl_lds16(pa0, ldsA0 + nb_); pa0 += 32;      \
        gl_lds16(pa1, ldsA1 + nb_); pa1 += 32;      \
        gl_lds16(pb0, ldsB0 + nb_); pb0 += 32;      \
        gl_lds16(pb1, ldsB1 + nb_); pb1 += 32;      \
    } while (0)

    STAGE_(0);
    if (kiters > 1) {
        STAGE_(1);
        asm volatile("s_waitcnt vmcnt(4)" ::: "memory");
    } else {
        asm volatile("s_waitcnt vmcnt(0)" ::: "memory");
    }
    __builtin_amdgcn_s_barrier();

    int cur = 0;
    for (int it = 0; it < kiters; ++it) {
        const u16* Aw = As + cur * 4096 + (w >> 1) * 2048;
        const u16* Bw = Bs + cur * 4096 + (w & 1) * 2048;
        bf16x8 af[4], bfr[4];
        #pragma unroll
        for (int i = 0; i < 4; ++i)
            af[i] = *(const bf16x8*)(Aw + ((i * 16 + l15) * 32 + quad * 8));
        #pragma unroll
        for (int j = 0; j < 4; ++j)
            bfr[j] = *(const bf16x8*)(Bw + ((j * 16 + l15) * 32 + quad * 8));
        asm volatile("s_waitcnt lgkmcnt(0)" ::: "memory");
        __builtin_amdgcn_sched_barrier(0);
        __builtin_amdgcn_s_barrier();
        const bool more2 = (it + 2 < kiters);
        if (more2) { STAGE_(cur); }
        __builtin_amdgcn_s_setprio(1);
        #pragma unroll
        for (int i = 0; i < 4; ++i)
            #pragma unroll
            for (int j = 0; j < 4; ++j)
                acc[i][j] = __builtin_amdgcn_mfma_f32_16x16x32_bf16(af[i], bfr[j], acc[i][j], 0, 0, 0);
        __builtin_amdgcn_s_setprio(0);
        if (it + 1 < kiters) {
            if (more2) asm volatile("s_waitcnt vmcnt(4)" ::: "memory");
            else       asm volatile("s_waitcnt vmcnt(0)" ::: "memory");
            __builtin_amdgcn_s_barrier();
        }
        cur ^= 1;
    }
#undef STAGE_
}

#define MFMA_CORE(AP, BP, LDA, LDB, KITERS)                              \
    __shared__ u16 As[2 * 128 * 32];                                     \
    __shared__ u16 Bs[2 * 128 * 32];                                     \
    const int t = threadIdx.x;                                           \
    const int wid = t >> 6, lane = t & 63;                               \
    const int quad = lane >> 4, l15 = lane & 15;                         \
    f32x4 acc[4][4];                                                     \
    _Pragma("unroll")                                                    \
    for (int i = 0; i < 4; ++i)                                          \
        _Pragma("unroll")                                                \
        for (int j = 0; j < 4; ++j) acc[i][j] = (f32x4){0.f,0.f,0.f,0.f};\
    mfma_mainloop(AP, BP, LDA, LDB, KITERS, acc, As, Bs);                \
    const int rbase = m0 + (wid >> 1) * 64;                              \
    const int cbase = n0 + (wid & 1) * 64;

// ---------------- R13 4-wave 8-phase 128x128 core, BK=64 (k3/k4) ----------------
// LDS elems: A [2][128][64] at 0 (16384), B at 16384. 65536 B total.
// Swizzle: LDS[r][c] = G[r][c ^ ((r&7)<<3)]. Stage ledger (HW-validated R13):
// {p0,p1: T1.A | p2,p3: N0.B | p4,p5: N0.A | p6,p7: N1.B}, vmcnt(4) at p3/p7.
// R16: staging via 4 monotone cursors (+64 elems/stage) — addresses identical
// to R13's, computed with 1 pointer add instead of full reconstruction.
#define PH_MID()  do { __builtin_amdgcn_sched_barrier(0);                 \
    __builtin_amdgcn_s_barrier();                                         \
    asm volatile("s_waitcnt lgkmcnt(0)" ::: "memory");                    \
    __builtin_amdgcn_sched_barrier(0);                                    \
    __builtin_amdgcn_s_setprio(1); } while (0)
#define PH_END()  do { __builtin_amdgcn_s_setprio(0);                     \
    __builtin_amdgcn_sched_barrier(0);                                    \
    __builtin_amdgcn_s_barrier(); } while (0)
#define PH_END_VM(n) do { __builtin_amdgcn_s_setprio(0);                  \
    asm volatile("s_waitcnt vmcnt(" #n ")" ::: "memory");                 \
    __builtin_amdgcn_sched_barrier(0);                                    \
    __builtin_amdgcn_s_barrier(); } while (0)

#define DSA4(d, mh, Ar)                                                   \
    _Pragma("unroll")                                                     \
    for (int mi = 0; mi < 2; ++mi) {                                      \
        Ar[mi][0] = *(const bf16x8*)(aB0 + (d) * 8192 + ((mh) * 2 + mi) * 1024); \
        Ar[mi][1] = *(const bf16x8*)(aB1 + (d) * 8192 + ((mh) * 2 + mi) * 1024); \
    }
#define DSB4(d, nh, Br)                                                   \
    _Pragma("unroll")                                                     \
    for (int ni = 0; ni < 2; ++ni) {                                      \
        Br[ni][0] = *(const bf16x8*)(bB0 + (d) * 8192 + ((nh) * 2 + ni) * 1024); \
        Br[ni][1] = *(const bf16x8*)(bB1 + (d) * 8192 + ((nh) * 2 + ni) * 1024); \
    }
#define MMQ4(mh, nh, Br)                                                  \
    _Pragma("unroll")                                                     \
    for (int kk = 0; kk < 2; ++kk)                                        \
        _Pragma("unroll")                                                 \
        for (int mi = 0; mi < 2; ++mi)                                    \
            _Pragma("unroll")                                             \
            for (int ni = 0; ni < 2; ++ni)                                \
                acc[(mh) * 2 + mi][(nh) * 2 + ni] =                       \
                    __builtin_amdgcn_mfma_f32_16x16x32_bf16(              \
                        a[mi][kk], Br[ni][kk],                            \
                        acc[(mh) * 2 + mi][(nh) * 2 + ni], 0, 0, 0);

__device__ __forceinline__ void mfma128_8p(
    const u16* __restrict__ gA, const u16* __restrict__ gB,
    int lda, int ldb, int ntiles,
    f32x4 (&acc)[4][4], u16* smem) {
    const int t = threadIdx.x;
    const int w = t >> 6, lane = t & 63;
    const int wr = w >> 1, wc = w & 1;
    const int quad = lane >> 4, l15 = lane & 15;

    // staging: thread t covers elems t*8 and 2048+t*8 of each 64x64 unit
    const int srow = t >> 3;                          // 0..31
    const int scol = (((t & 7) ^ (srow & 7)) << 3);   // pre-swizzled source col

    // monotone unit cursors (each staged once per K-tile, in tile order)
    const size_t a32 = (size_t)32 * lda;
    const size_t b32 = (size_t)32 * ldb;
    const u16* cA0 = gA + (size_t)srow * lda + scol;          // A rows 0..63
    const u16* cA1 = gA + (size_t)(64 + srow) * lda + scol;   // A rows 64..127
    const u16* cB0 = gB + (size_t)srow * ldb + scol;
    const u16* cB1 = gB + (size_t)(64 + srow) * ldb + scol;

#define SGA0(d) do { u16* s_ = smem + (d) * 8192 + t * 8;                 \
    gl_lds16(cA0, s_); gl_lds16(cA0 + a32, s_ + 2048); cA0 += 64; } while (0)
#define SGA1(d) do { u16* s_ = smem + (d) * 8192 + 4096 + t * 8;          \
    gl_lds16(cA1, s_); gl_lds16(cA1 + a32, s_ + 2048); cA1 += 64; } while (0)
#define SGB0(d) do { u16* s_ = smem + 16384 + (d) * 8192 + t * 8;         \
    gl_lds16(cB0, s_); gl_lds16(cB0 + b32, s_ + 2048); cB0 += 64; } while (0)
#define SGB1(d) do { u16* s_ = smem + 16384 + (d) * 8192 + 4096 + t * 8;  \
    gl_lds16(cB1, s_); gl_lds16(cB1 + b32, s_ + 2048); cB1 += 64; } while (0)

    // reads: swizzled slot addressing
    const int q = (quad * 8) ^ ((l15 & 7) << 3);
    const u16* aB0 = smem + (wr * 64 + l15) * 64 + q;
    const u16* aB1 = smem + (wr * 64 + l15) * 64 + (q ^ 32);
    const u16* bB0 = smem + 16384 + (wc * 64 + l15) * 64 + q;
    const u16* bB1 = smem + 16384 + (wc * 64 + l15) * 64 + (q ^ 32);

    // prologue: T0 {A0,A1,B0,B1} -> buf0 ; T1 {B0,B1} -> buf1 (12 loads)
    SGA0(0); SGA1(0); SGB0(0); SGB1(0);
    SGB0(1); SGB1(1);
    asm volatile("s_waitcnt vmcnt(4)" ::: "memory");   // retire T0 (8 loads)
    __builtin_amdgcn_s_barrier();

    bf16x8 a[2][2], b[2][2], c[2][2];
    const int NI = ntiles >> 1;
    for (int i = 0; i < NI - 1; ++i) {
        // p0
        DSA4(0, 0, a) DSB4(0, 0, b)
        SGA0(1);
        PH_MID(); MMQ4(0, 0, b) PH_END();
        // p1
        DSB4(0, 1, c)
        SGA1(1);
        PH_MID(); MMQ4(0, 1, c) PH_END();
        // p2
        DSA4(0, 1, a)
        SGB0(0);
        PH_MID(); MMQ4(1, 1, c) PH_END();
        // p3
        SGB1(0);
        PH_MID(); MMQ4(1, 0, b) PH_END_VM(4);
        // p4
        DSA4(1, 0, a) DSB4(1, 0, b)
        SGA0(0);
        PH_MID(); MMQ4(0, 0, b) PH_END();
        // p5
        DSB4(1, 1, c)
        SGA1(0);
        PH_MID(); MMQ4(0, 1, c) PH_END();
        // p6
        DSA4(1, 1, a)
        SGB0(1);
        PH_MID(); MMQ4(1, 1, c) PH_END();
        // p7
        SGB1(1);
        PH_MID(); MMQ4(1, 0, b) PH_END_VM(4);
    }
    // tail: buf0 = tile ntiles-2, buf1 = tile ntiles-1; stage only buf1.A
    {
        DSA4(0, 0, a) DSB4(0, 0, b)
        SGA0(1);
        PH_MID(); MMQ4(0, 0, b) PH_END();
        DSB4(0, 1, c)
        SGA1(1);
        PH_MID(); MMQ4(0, 1, c) PH_END();
        DSA4(0, 1, a)
        PH_MID(); MMQ4(1, 1, c) PH_END();
        PH_MID(); MMQ4(1, 0, b) PH_END_VM(0);
        DSA4(1, 0, a) DSB4(1, 0, b)
        PH_MID(); MMQ4(0, 0, b) PH_END();
        DSB4(1, 1, c)
        PH_MID(); MMQ4(0, 1, c) PH_END();
        DSA4(1, 1, a)
        PH_MID(); MMQ4(1, 1, c) PH_END();
        PH_MID(); MMQ4(1, 0, b)
        __builtin_amdgcn_s_setprio(0);
    }
#undef SGA0
#undef SGA1
#undef SGB0
#undef SGB1
}

// k1: h1[(b*C+c)][t] = yat(xT, twb); M=49152 N=384 K=224 (R9 core).
__global__ __launch_bounds__(256) void k1_token_yat(
    const u16* __restrict__ xT, const u16* __restrict__ twb,
    const float* __restrict__ tb, const float* __restrict__ twn,
    const float* __restrict__ xn1, const float* __restrict__ alpha, float sb,
    u16* __restrict__ h1) {
    const int m0 = (blockIdx.x + blockIdx.y * 8) * 128;
    const int n0 = blockIdx.z * 128;
    MFMA_CORE(xT + (size_t)m0 * PPAD, twb + (size_t)n0 * PPAD, PPAD, PPAD, PPAD / 32)
    float scale = powf(sqrtf(sb), alpha[0]);
    #pragma unroll
    for (int i = 0; i < 4; ++i) {
        #pragma unroll
        for (int j = 0; j < 4; ++j) {
            int col = cbase + j * 16 + l15;
            float bn = tb[col], wnn = twn[col];
            #pragma unroll
            for (int reg = 0; reg < 4; ++reg) {
                int row = rbase + i * 16 + quad * 4 + reg;
                float dnb = acc[i][j][reg];
                float dot = dnb + bn;
                float dist = wnn + xn1[row] - 2.f * dnb;
                float r = __builtin_amdgcn_rcpf(dist + EPSY);
                h1[(size_t)row * TM_ + col] = f2bf(scale * dot * dot * r);
            }
        }
    }
}

// k3: h3 = yat(x1b, cwb); M=12544 N=3072 K=768. 4-wave 8-phase 128² core.
// grid (8,13,24): mt = x + y*8 (XCD stripe, guard <98), n-tile = z.
__global__ __launch_bounds__(256) void k3_chan_yat(
    const u16* __restrict__ x1b, const u16* __restrict__ cwb,
    const float* __restrict__ cb, const float* __restrict__ cwn,
    const float* __restrict__ xn2, const float* __restrict__ alpha, float sb,
    u16* __restrict__ h3) {
    __shared__ __align__(16) u16 smem[32768];
    const int mt = blockIdx.x + blockIdx.y * 8;
    if (mt >= (B_ * P_) / 128) return;
    const int m0 = mt * 128;
    const int n0 = blockIdx.z * 128;
    const int t = threadIdx.x;
    const int w = t >> 6, l = t & 63;
    const int wr = w >> 1, wc = w & 1;
    const int quad = l >> 4, l15 = l & 15;
    f32x4 acc[4][4];
    #pragma unroll
    for (int m = 0; m < 4; ++m)
        #pragma unroll
        for (int n = 0; n < 4; ++n) acc[m][n] = (f32x4){0.f, 0.f, 0.f, 0.f};
    mfma128_8p(x1b + (size_t)m0 * C_, cwb + (size_t)n0 * C_,
               C_, C_, C_ / 64, acc, smem);
    const int rbase = m0 + wr * 64;
    const int cbase = n0 + wc * 64;
    float scale = powf(sqrtf(sb), alpha[0]);
    #pragma unroll
    for (int m = 0; m < 4; ++m) {
        #pragma unroll
        for (int n = 0; n < 4; ++n) {
            int col = cbase + n * 16 + l15;
            float bn = cb[col], wnn = cwn[col];
            #pragma unroll
            for (int reg = 0; reg < 4; ++reg) {
                int row = rbase + m * 16 + quad * 4 + reg;
                float dnb = acc[m][n][reg];
                float dot = dnb + bn;
                float dist = wnn + xn2[row] - 2.f * dnb;
                float r = __builtin_amdgcn_rcpf(dist + EPSY);
                h3[(size_t)row * CM_ + col] = f2bf(scale * dot * dot * r);
            }
        }
    }
}

// k2: x1b = bf16(x + w2 . h1[b]^T + b2); fused xn2 row-norm atomics (R9 core).
__global__ __launch_bounds__(256) void k2_token_out(
    const u16* __restrict__ w2b, const u16* __restrict__ h1,
    const float* __restrict__ b2, const float* __restrict__ x,
    float* __restrict__ xn2, u16* __restrict__ x1b) {
    const int m0 = blockIdx.x * 128, n0 = blockIdx.y * 128;
    const u16* Bz = h1 + (size_t)blockIdx.z * C_ * TM_;
    MFMA_CORE(w2b + (size_t)m0 * TM_, Bz + (size_t)n0 * TM_, TM_, TM_, TM_ / 32)
    const float* rz = x + (size_t)blockIdx.z * P_ * C_;
    u16* oz = x1b + (size_t)blockIdx.z * P_ * C_;
    float* xrow = xn2 + (size_t)blockIdx.z * P_;
    #pragma unroll
    for (int i = 0; i < 4; ++i) {
        #pragma unroll
        for (int reg = 0; reg < 4; ++reg) {
            int row = rbase + i * 16 + quad * 4 + reg;
            if (row < P_) {
                float bm = b2[row];
                float s = 0.f;
                #pragma unroll
                for (int j = 0; j < 4; ++j) {
                    int col = cbase + j * 16 + l15;
                    float v = acc[i][j][reg] + bm + rz[(size_t)row * C_ + col];
                    u16 h = f2bf(v);
                    oz[(size_t)row * C_ + col] = h;
                    float vb = bf2f(h);
                    s = fmaf(vb, vb, s);
                }
                s += __shfl_xor(s, 1, 64);
                s += __shfl_xor(s, 2, 64);
                s += __shfl_xor(s, 4, 64);
                s += __shfl_xor(s, 8, 64);
                if (l15 == 0) atomicAdd(&xrow[row], s);
            }
        }
    }
}

// k4 split-K on the 4-wave 128² core: grid (8,13,6*nsplit):
// mt = x + y*8 (guard <98), n0 = (z%6)*128, ks = z/6.
__global__ __launch_bounds__(256) void k4_split(
    const u16* __restrict__ h3, const u16* __restrict__ w4b,
    u16* __restrict__ pbuf, int KK) {
    __shared__ __align__(16) u16 smem[32768];
    const int mt = blockIdx.x + blockIdx.y * 8;
    if (mt >= (B_ * P_) / 128) return;
    const int m0 = mt * 128;
    const int nz = blockIdx.z;
    const int n0 = (nz % (C_ / 128)) * 128;
    const int ks = nz / (C_ / 128);
    const int kbase = ks * KK;
    const int t = threadIdx.x;
    const int w = t >> 6, l = t & 63;
    const int wr = w >> 1, wc = w & 1;
    const int quad = l >> 4, l15 = l & 15;
    f32x4 acc[4][4];
    #pragma unroll
    for (int m = 0; m < 4; ++m)
        #pragma unroll
        for (int n = 0; n < 4; ++n) acc[m][n] = (f32x4){0.f, 0.f, 0.f, 0.f};
    mfma128_8p(h3 + (size_t)m0 * CM_ + kbase, w4b + (size_t)n0 * CM_ + kbase,
               CM_, CM_, KK / 64, acc, smem);
    const int rbase = m0 + wr * 64;
    const int cbase = n0 + wc * 64;
    u16* dst = pbuf + (size_t)ks * ((size_t)B_ * P_ * C_);
    #pragma unroll
    for (int m = 0; m < 4; ++m) {
        #pragma unroll
        for (int n = 0; n < 4; ++n) {
            int col = cbase + n * 16 + l15;
            #pragma unroll
            for (int reg = 0; reg < 4; ++reg) {
                int row = rbase + m * 16 + quad * 4 + reg;
                dst[(size_t)row * C_ + col] = f2bf(acc[m][n][reg]);
            }
        }
    }
}

// reduce: out = sum(bf16 pbuf[0..NS-1]) + bf2f(x1b) + b4
template <int NS>
__global__ __launch_bounds__(256) void k4_reduce(
    float* __restrict__ outp, const u16* __restrict__ pbuf,
    const u16* __restrict__ x1b, const float* __restrict__ b4) {
    int idx = blockIdx.x * 256 + threadIdx.x;      // < B*P*C/4
    int c = (idx * 4) % C_;
    ushort4 r = ((const ushort4*)x1b)[idx];
    float4 o;
    o.x = bf2f(r.x) + b4[c + 0];
    o.y = bf2f(r.y) + b4[c + 1];
    o.z = bf2f(r.z) + b4[c + 2];
    o.w = bf2f(r.w) + b4[c + 3];
    const size_t stride4 = (size_t)B_ * P_ * C_ / 4;
    #pragma unroll
    for (int s = 0; s < NS; ++s) {
        ushort4 p = ((const ushort4*)pbuf)[idx + s * stride4];
        o.x += bf2f(p.x); o.y += bf2f(p.y); o.z += bf2f(p.z); o.w += bf2f(p.w);
    }
    ((float4*)outp)[idx] = o;
}

// fallback k4 (tiny ws): 128x64 tile BK=32
__global__ __launch_bounds__(256) void gemm_k4_fb(
    const u16* __restrict__ A, const u16* __restrict__ Bmat,
    const float* __restrict__ biasN, const u16* __restrict__ resB,
    float* __restrict__ Fout) {
    __shared__ u16 As[128 * 32];
    __shared__ u16 Bs[64 * 32];
    const int t = threadIdx.x;
    const int wid = t >> 6, lane = t & 63;
    const int quad = lane >> 4, l15 = lane & 15;
    const int m0 = blockIdx.x * 128, n0 = blockIdx.y * 64;
    f32x4 acc[4][2];
    #pragma unroll
    for (int i = 0; i < 4; ++i)
        #pragma unroll
        for (int j = 0; j < 2; ++j) acc[i][j] = (f32x4){0.f, 0.f, 0.f, 0.f};
    const u16* Aw = As + (wid >> 1) * (64 * 32);
    const u16* Bw = Bs + (wid & 1) * (32 * 32);
    const int arow = t >> 2, akc = (t & 3) * 8;
    for (int k0 = 0; k0 < CM_; k0 += 32) {
        gl_lds16(A + (size_t)(m0 + arow) * CM_ + k0 + akc,      As + wid * 512);
        gl_lds16(A + (size_t)(m0 + 64 + arow) * CM_ + k0 + akc, As + 2048 + wid * 512);
        gl_lds16(Bmat + (size_t)(n0 + arow) * CM_ + k0 + akc,   Bs + wid * 512);
        __syncthreads();
        bf16x8 af[4], bfr[2];
        #pragma unroll
        for (int i = 0; i < 4; ++i)
            af[i] = *(const bf16x8*)(Aw + ((i * 16 + l15) * 32 + quad * 8));
        #pragma unroll
        for (int j = 0; j < 2; ++j)
            bfr[j] = *(const bf16x8*)(Bw + ((j * 16 + l15) * 32 + quad * 8));
        #pragma unroll
        for (int i = 0; i < 4; ++i)
            #pragma unroll
            for (int j = 0; j < 2; ++j)
                acc[i][j] = __builtin_amdgcn_mfma_f32_16x16x32_bf16(af[i], bfr[j], acc[i][j], 0, 0, 0);
        __syncthreads();
    }
    const int rbase = m0 + (wid >> 1) * 64;
    const int cbase = n0 + (wid & 1) * 32;
    #pragma unroll
    for (int i = 0; i < 4; ++i) {
        #pragma unroll
        for (int j = 0; j < 2; ++j) {
            int col = cbase + j * 16 + l15;
            float bn = biasN[col];
            #pragma unroll
            for (int reg = 0; reg < 4; ++reg) {
                int row = rbase + i * 16 + quad * 4 + reg;
                float v = acc[i][j][reg] + bn + bf2f(resB[(size_t)row * C_ + col]);
                Fout[(size_t)row * C_ + col] = v;
            }
        }
    }
}

extern "C" void kernel_launch(void* const* d_in, const int* in_sizes, int n_in,
                              void* d_out, int out_size, void* d_ws, size_t ws_size,
                              hipStream_t stream) {
    const float* x  = (const float*)d_in[0];
    const float* tw = (const float*)d_in[1];
    const float* tb = (const float*)d_in[2];
    const float* ta = (const float*)d_in[3];
    const float* w2 = (const float*)d_in[4];
    const float* b2 = (const float*)d_in[5];
    const float* cw = (const float*)d_in[6];
    const float* cb = (const float*)d_in[7];
    const float* ca = (const float*)d_in[8];
    const float* w4 = (const float*)d_in[9];
    const float* b4 = (const float*)d_in[10];
    float* out = (float*)d_out;

    // ---- workspace layout (aliased) ----
    char* ws = (char*)d_ws;
    u16* h1 = (u16*)ws;                                    // B*C*TM (37.7 MB)
    u16* xT = (u16*)(ws + 37748736);                       // (B*C) x 224 (22 MB)
    u16* h3 = (u16*)ws;                                    // (B*P) x CM (77 MB)
    size_t off = 77070336;
    u16* x1b = (u16*)(ws + off); off += (size_t)B_ * P_ * C_ * 2;
    u16* twb = (u16*)(ws + off); off += (size_t)TM_ * PPAD * 2;
    u16* w2b = (u16*)(ws + off); off += (size_t)256 * TM_ * 2;
    u16* cwb = (u16*)(ws + off); off += (size_t)CM_ * C_ * 2;
    u16* w4b = (u16*)(ws + off); off += (size_t)C_ * CM_ * 2;
    float* xn1 = (float*)(ws + off); off += (size_t)B_ * C_ * 4;
    float* xn2 = (float*)(ws + off); off += (size_t)B_ * P_ * 4;
    float* twn = (float*)(ws + off); off += (size_t)TM_ * 4;
    float* cwn = (float*)(ws + off); off += (size_t)CM_ * 4;
    u16* pbuf = (u16*)(ws + off);                          // bf16 split-K partials
    const size_t psz = (size_t)B_ * P_ * C_ * 2;           // 19,267,584 per buffer

    int nsplit = 1;
    if (ws_size >= off + 4 * psz)      nsplit = 4;
    else if (ws_size >= off + 2 * psz) nsplit = 2;

    const float SBT = (float)TM_ / logf((float)TM_ + 1.0f);
    const float SBC = (float)CM_ / logf((float)CM_ + 1.0f);

    // ---- prep ----
    hipMemsetAsync(xn1, 0, (size_t)(B_ * C_ + B_ * P_) * 4, stream);
    k_prep_weights<<<3552, 256, 0, stream>>>(tw, twb, twn, cw, cwb, cwn,
                                             w2, w2b, w4, w4b);
    k_prep_xT<<<dim3(PPAD / 32, C_ / 32, B_), 256, 0, stream>>>(x, xT, xn1);

    // ---- k1: M=49152 N=384 K=224 ; R9 core, XCD-swizzled grid (8,48,3) ----
    k1_token_yat<<<dim3(8, 48, 3), 256, 0, stream>>>(
        xT, twb, tb, twn, xn1, ta, SBT, h1);

    // ---- k2: M=256 N=768 K=384, per-batch ; R9 core ----
    k2_token_out<<<dim3(2, C_ / 128, B_), 256, 0, stream>>>(
        w2b, h1, b2, x, xn2, x1b);

    // ---- k3: M=12544 N=3072 K=768 ; 4-wave 128² 8-phase, grid (8,13,24) ----
    k3_chan_yat<<<dim3(8, 13, 24), 256, 0, stream>>>(
        x1b, cwb, cb, cwn, xn2, ca, SBC, h3);

    // ---- k4: M=12544 N=768 K=3072, split-K bf16 partials, 8p core ----
    if (nsplit > 1) {
        k4_split<<<dim3(8, 13, (C_ / 128) * nsplit), 256, 0, stream>>>(
            h3, w4b, pbuf, CM_ / nsplit);
        int n4 = B_ * P_ * C_ / 4;
        if (nsplit == 4)
            k4_reduce<4><<<(n4 + 255) / 256, 256, 0, stream>>>(out, pbuf, x1b, b4);
        else
            k4_reduce<2><<<(n4 + 255) / 256, 256, 0, stream>>>(out, pbuf, x1b, b4);
    } else {
        gemm_k4_fb<<<dim3(B_ * P_ / 128, C_ / 64), 256, 0, stream>>>(
            h3, w4b, b4, x1b, out);
    }
}

// Round 10
// 363.250 us; speedup vs baseline: 1.0836x; 1.0106x over previous
//
#include <hip/hip_runtime.h>
#include <hip/hip_bf16.h>
#include <math.h>

// MixerBlock on MI355X — R17: R16 + early-issue ds_reads in the 8p core.
// All 16 b128 reads of a half-iteration issue at its publish boundary
// (p0 for buf0, p4 for buf1), in consumption order (a0,b,c,a1); the manual
// lgkmcnt(0) is dropped so the compiler emits counted lgkm waits before each
// MFMA — removes ~200cy exposed LDS latency from 6 of 8 phases (phase cost
// was ~470cy vs 78cy MFMA; MfmaUtil 31%). Stage/vmcnt/barrier skeleton is
// byte-identical to R13/R16 (hazard ledger re-verified under read motion).
// +16 VGPR (4 live frag sets) -> launch_bounds(256,2); LDS still caps
// residency at 2 blocks/CU. k1/k2 keep the R9 2-deep core.
#define B_   64
#define P_   196
#define PPAD 224
#define C_   768
#define TM_  384
#define CM_  3072
#define EPSY 0.1f

typedef unsigned short u16;
typedef __attribute__((ext_vector_type(8))) short bf16x8;
typedef __attribute__((ext_vector_type(4))) float f32x4;

__device__ __forceinline__ float bf2f(u16 v) {
    return __uint_as_float(((unsigned int)v) << 16);
}
__device__ __forceinline__ u16 f2bf(float f) {
    unsigned int u = __float_as_uint(f);
    unsigned int rounding = 0x7FFFu + ((u >> 16) & 1u);
    return (u16)((u + rounding) >> 16);
}

__device__ __forceinline__ void gl_lds16(const u16* g, u16* l) {
    __builtin_amdgcn_global_load_lds(
        (const __attribute__((address_space(1))) unsigned int*)g,
        (__attribute__((address_space(3))) unsigned int*)l,
        16, 0, 0);
}

// ---------------- prep ----------------

__global__ __launch_bounds__(256) void k_prep_xT(const float* __restrict__ x,
                                                 u16* __restrict__ xT,
                                                 float* __restrict__ xn1) {
    __shared__ u16 tile[32][33];
    __shared__ float colsum[32];
    const int b = blockIdx.z, p0 = blockIdx.x * 32, c0 = blockIdx.y * 32;
    const int tx = threadIdx.x & 31, ty = threadIdx.x >> 5;
    if (threadIdx.x < 32) colsum[threadIdx.x] = 0.f;
    const float* xb = x + (size_t)b * P_ * C_;
    float s = 0.f;
    #pragma unroll
    for (int r = 0; r < 4; ++r) {
        int p = p0 + ty + r * 8;
        float v = (p < P_) ? xb[(size_t)p * C_ + c0 + tx] : 0.f;
        u16 h = f2bf(v);
        tile[ty + r * 8][tx] = h;
        float vb = bf2f(h);
        s = fmaf(vb, vb, s);
    }
    __syncthreads();
    u16* dst = xT + ((size_t)b * C_ + c0) * PPAD + p0;
    #pragma unroll
    for (int r = 0; r < 4; ++r) {
        int cl = ty + r * 8;
        dst[(size_t)cl * PPAD + tx] = tile[tx][cl];
    }
    atomicAdd(&colsum[tx], s);
    __syncthreads();
    if (threadIdx.x < 32)
        atomicAdd(&xn1[(size_t)b * C_ + c0 + threadIdx.x], colsum[threadIdx.x]);
}

__device__ __forceinline__ void pad_norm_body(const float* in, u16* outb, float* norm,
                                              int rows, int inlen, int outlen,
                                              int bid, int tid) {
    int wave = (bid * 256 + tid) >> 6;
    int lane = tid & 63;
    if (wave >= rows) return;
    const float* src = in + (size_t)wave * inlen;
    u16* dst = outb + (size_t)wave * outlen;
    float s = 0.f;
    for (int i = lane; i < outlen; i += 64) {
        float v = (i < inlen) ? src[i] : 0.f;
        u16 h = f2bf(v);
        dst[i] = h;
        float vv = bf2f(h);
        s = fmaf(vv, vv, s);
    }
    #pragma unroll
    for (int off = 32; off > 0; off >>= 1) s += __shfl_down(s, off, 64);
    if (lane == 0) norm[wave] = s;
}

__global__ __launch_bounds__(256) void k_prep_weights(
    const float* __restrict__ tw, u16* __restrict__ twb, float* __restrict__ twn,
    const float* __restrict__ cw, u16* __restrict__ cwb, float* __restrict__ cwn,
    const float* __restrict__ w2, u16* __restrict__ w2b,
    const float* __restrict__ w4, u16* __restrict__ w4b) {
    int bid = blockIdx.x, tid = threadIdx.x;
    if (bid < 96) {
        pad_norm_body(tw, twb, twn, TM_, P_, PPAD, bid, tid);
    } else if (bid < 864) {
        pad_norm_body(cw, cwb, cwn, CM_, C_, C_, bid - 96, tid);
    } else if (bid < 1248) {
        int idx = (bid - 864) * 256 + tid;
        int row = idx / TM_;
        w2b[idx] = (row < P_) ? f2bf(w2[(size_t)row * TM_ + (idx % TM_)]) : (u16)0;
    } else {
        int idx = (bid - 1248) * 256 + tid;
        float4 v = ((const float4*)w4)[idx];
        ushort4 o;
        o.x = f2bf(v.x); o.y = f2bf(v.y); o.z = f2bf(v.z); o.w = f2bf(v.w);
        ((ushort4*)w4b)[idx] = o;
    }
}

// ---------------- R9 128x128 core (k1/k2: short-K shapes) ----------------
__device__ __forceinline__ void mfma_mainloop(
    const u16* __restrict__ A, const u16* __restrict__ B,
    int lda, int ldb, int kiters,
    f32x4 (&acc)[4][4], u16* As, u16* Bs) {
    const int t = threadIdx.x;
    const int w = t >> 6, l = t & 63;
    const int quad = l >> 4, l15 = l & 15;
    const int row0 = t >> 2, kc = (t & 3) * 8;

    const u16* pa0 = A + (size_t)row0 * lda + kc;
    const u16* pa1 = A + (size_t)(64 + row0) * lda + kc;
    const u16* pb0 = B + (size_t)row0 * ldb + kc;
    const u16* pb1 = B + (size_t)(64 + row0) * ldb + kc;

    u16* ldsA0 = As + w * 512;
    u16* ldsA1 = As + 2048 + w * 512;
    u16* ldsB0 = Bs + w * 512;
    u16* ldsB1 = Bs + 2048 + w * 512;

#define STAGE_(bsel)                                \
    do {                                            \
        const int nb_ = (bsel) * 4096;              \
        gl_lds16(pa0, ldsA0 + nb_); pa0 += 32;      \
        gl_lds16(pa1, ldsA1 + nb_); pa1 += 32;      \
        gl_lds16(pb0, ldsB0 + nb_); pb0 += 32;      \
        gl_lds16(pb1, ldsB1 + nb_); pb1 += 32;      \
    } while (0)

    STAGE_(0);
    if (kiters > 1) {
        STAGE_(1);
        asm volatile("s_waitcnt vmcnt(4)" ::: "memory");
    } else {
        asm volatile("s_waitcnt vmcnt(0)" ::: "memory");
    }
    __builtin_amdgcn_s_barrier();

    int cur = 0;
    for (int it = 0; it < kiters; ++it) {
        const u16* Aw = As + cur * 4096 + (w >> 1) * 2048;
        const u16* Bw = Bs + cur * 4096 + (w & 1) * 2048;
        bf16x8 af[4], bfr[4];
        #pragma unroll
        for (int i = 0; i < 4; ++i)
            af[i] = *(const bf16x8*)(Aw + ((i * 16 + l15) * 32 + quad * 8));
        #pragma unroll
        for (int j = 0; j < 4; ++j)
            bfr[j] = *(const bf16x8*)(Bw + ((j * 16 + l15) * 32 + quad * 8));
        asm volatile("s_waitcnt lgkmcnt(0)" ::: "memory");
        __builtin_amdgcn_sched_barrier(0);
        __builtin_amdgcn_s_barrier();
        const bool more2 = (it + 2 < kiters);
        if (more2) { STAGE_(cur); }
        __builtin_amdgcn_s_setprio(1);
        #pragma unroll
        for (int i = 0; i < 4; ++i)
            #pragma unroll
            for (int j = 0; j < 4; ++j)
                acc[i][j] = __builtin_amdgcn_mfma_f32_16x16x32_bf16(af[i], bfr[j], acc[i][j], 0, 0, 0);
        __builtin_amdgcn_s_setprio(0);
        if (it + 1 < kiters) {
            if (more2) asm volatile("s_waitcnt vmcnt(4)" ::: "memory");
            else       asm volatile("s_waitcnt vmcnt(0)" ::: "memory");
            __builtin_amdgcn_s_barrier();
        }
        cur ^= 1;
    }
#undef STAGE_
}

#define MFMA_CORE(AP, BP, LDA, LDB, KITERS)                              \
    __shared__ u16 As[2 * 128 * 32];                                     \
    __shared__ u16 Bs[2 * 128 * 32];                                     \
    const int t = threadIdx.x;                                           \
    const int wid = t >> 6, lane = t & 63;                               \
    const int quad = lane >> 4, l15 = lane & 15;                         \
    f32x4 acc[4][4];                                                     \
    _Pragma("unroll")                                                    \
    for (int i = 0; i < 4; ++i)                                          \
        _Pragma("unroll")                                                \
        for (int j = 0; j < 4; ++j) acc[i][j] = (f32x4){0.f,0.f,0.f,0.f};\
    mfma_mainloop(AP, BP, LDA, LDB, KITERS, acc, As, Bs);                \
    const int rbase = m0 + (wid >> 1) * 64;                              \
    const int cbase = n0 + (wid & 1) * 64;

// ---------------- R17 4-wave 8-phase 128x128 core, BK=64 (k3/k4) ----------------
// LDS elems: A [2][128][64] at 0 (16384), B at 16384. 65536 B total.
// Swizzle: LDS[r][c] = G[r][c ^ ((r&7)<<3)]. Stage ledger (HW-validated R13):
// {p0,p1: T1.A | p2,p3: N0.B | p4,p5: N0.A | p6,p7: N1.B}, vmcnt(4) at p3/p7.
// R17: all 16 ds_reads of a half-iter issue at its publish boundary (p0/p4);
// compiler emits counted lgkm waits before each MFMA (no manual lgkm(0)).
#define PH2()  do { __builtin_amdgcn_sched_barrier(0);                    \
    __builtin_amdgcn_s_barrier();                                         \
    __builtin_amdgcn_sched_barrier(0);                                    \
    __builtin_amdgcn_s_setprio(1); } while (0)
#define PH_END()  do { __builtin_amdgcn_s_setprio(0);                     \
    __builtin_amdgcn_sched_barrier(0);                                    \
    __builtin_amdgcn_s_barrier(); } while (0)
#define PH_END_VM(n) do { __builtin_amdgcn_s_setprio(0);                  \
    asm volatile("s_waitcnt vmcnt(" #n ")" ::: "memory");                 \
    __builtin_amdgcn_sched_barrier(0);                                    \
    __builtin_amdgcn_s_barrier(); } while (0)

#define DSA4(d, mh, Ar)                                                   \
    _Pragma("unroll")                                                     \
    for (int mi = 0; mi < 2; ++mi) {                                      \
        Ar[mi][0] = *(const bf16x8*)(aB0 + (d) * 8192 + ((mh) * 2 + mi) * 1024); \
        Ar[mi][1] = *(const bf16x8*)(aB1 + (d) * 8192 + ((mh) * 2 + mi) * 1024); \
    }
#define DSB4(d, nh, Br)                                                   \
    _Pragma("unroll")                                                     \
    for (int ni = 0; ni < 2; ++ni) {                                      \
        Br[ni][0] = *(const bf16x8*)(bB0 + (d) * 8192 + ((nh) * 2 + ni) * 1024); \
        Br[ni][1] = *(const bf16x8*)(bB1 + (d) * 8192 + ((nh) * 2 + ni) * 1024); \
    }
#define MMQ5(mh, nh, Ar, Br)                                              \
    _Pragma("unroll")                                                     \
    for (int kk = 0; kk < 2; ++kk)                                        \
        _Pragma("unroll")                                                 \
        for (int mi = 0; mi < 2; ++mi)                                    \
            _Pragma("unroll")                                             \
            for (int ni = 0; ni < 2; ++ni)                                \
                acc[(mh) * 2 + mi][(nh) * 2 + ni] =                       \
                    __builtin_amdgcn_mfma_f32_16x16x32_bf16(              \
                        Ar[mi][kk], Br[ni][kk],                           \
                        acc[(mh) * 2 + mi][(nh) * 2 + ni], 0, 0, 0);

__device__ __forceinline__ void mfma128_8p(
    const u16* __restrict__ gA, const u16* __restrict__ gB,
    int lda, int ldb, int ntiles,
    f32x4 (&acc)[4][4], u16* smem) {
    const int t = threadIdx.x;
    const int w = t >> 6, lane = t & 63;
    const int wr = w >> 1, wc = w & 1;
    const int quad = lane >> 4, l15 = lane & 15;

    // staging: thread t covers elems t*8 and 2048+t*8 of each 64x64 unit
    const int srow = t >> 3;                          // 0..31
    const int scol = (((t & 7) ^ (srow & 7)) << 3);   // pre-swizzled source col

    // monotone unit cursors (each staged once per K-tile, in tile order)
    const size_t a32 = (size_t)32 * lda;
    const size_t b32 = (size_t)32 * ldb;
    const u16* cA0 = gA + (size_t)srow * lda + scol;          // A rows 0..63
    const u16* cA1 = gA + (size_t)(64 + srow) * lda + scol;   // A rows 64..127
    const u16* cB0 = gB + (size_t)srow * ldb + scol;
    const u16* cB1 = gB + (size_t)(64 + srow) * ldb + scol;

#define SGA0(d) do { u16* s_ = smem + (d) * 8192 + t * 8;                 \
    gl_lds16(cA0, s_); gl_lds16(cA0 + a32, s_ + 2048); cA0 += 64; } while (0)
#define SGA1(d) do { u16* s_ = smem + (d) * 8192 + 4096 + t * 8;          \
    gl_lds16(cA1, s_); gl_lds16(cA1 + a32, s_ + 2048); cA1 += 64; } while (0)
#define SGB0(d) do { u16* s_ = smem + 16384 + (d) * 8192 + t * 8;         \
    gl_lds16(cB0, s_); gl_lds16(cB0 + b32, s_ + 2048); cB0 += 64; } while (0)
#define SGB1(d) do { u16* s_ = smem + 16384 + (d) * 8192 + 4096 + t * 8;  \
    gl_lds16(cB1, s_); gl_lds16(cB1 + b32, s_ + 2048); cB1 += 64; } while (0)

    // reads: swizzled slot addressing
    const int q = (quad * 8) ^ ((l15 & 7) << 3);
    const u16* aB0 = smem + (wr * 64 + l15) * 64 + q;
    const u16* aB1 = smem + (wr * 64 + l15) * 64 + (q ^ 32);
    const u16* bB0 = smem + 16384 + (wc * 64 + l15) * 64 + q;
    const u16* bB1 = smem + 16384 + (wc * 64 + l15) * 64 + (q ^ 32);

    // prologue: T0 {A0,A1,B0,B1} -> buf0 ; T1 {B0,B1} -> buf1 (12 loads)
    SGA0(0); SGA1(0); SGB0(0); SGB1(0);
    SGB0(1); SGB1(1);
    asm volatile("s_waitcnt vmcnt(4)" ::: "memory");   // retire T0 (8 loads)
    __builtin_amdgcn_s_barrier();

    bf16x8 a0[2][2], a1[2][2], b[2][2], c[2][2];
    const int NI = ntiles >> 1;
    for (int i = 0; i < NI - 1; ++i) {
        // p0: buf0 published (prev p7 / prologue) — issue ALL buf0 reads,
        // in consumption order: a0 (p0), b (p0,p3), c (p1,p2), a1 (p2,p3).
        DSA4(0, 0, a0) DSB4(0, 0, b) DSB4(0, 1, c) DSA4(0, 1, a1)
        SGA0(1);
        PH2(); MMQ5(0, 0, a0, b) PH_END();
        // p1
        SGA1(1);
        PH2(); MMQ5(0, 1, a0, c) PH_END();
        // p2
        SGB0(0);
        PH2(); MMQ5(1, 1, a1, c) PH_END();
        // p3
        SGB1(0);
        PH2(); MMQ5(1, 0, a1, b) PH_END_VM(4);
        // p4: buf1 published (p3 barrier) — issue ALL buf1 reads.
        DSA4(1, 0, a0) DSB4(1, 0, b) DSB4(1, 1, c) DSA4(1, 1, a1)
        SGA0(0);
        PH2(); MMQ5(0, 0, a0, b) PH_END();
        // p5
        SGA1(0);
        PH2(); MMQ5(0, 1, a0, c) PH_END();
        // p6
        SGB0(1);
        PH2(); MMQ5(1, 1, a1, c) PH_END();
        // p7
        SGB1(1);
        PH2(); MMQ5(1, 0, a1, b) PH_END_VM(4);
    }
    // tail: buf0 = tile ntiles-2, buf1 = tile ntiles-1; stage only buf1.A
    {
        DSA4(0, 0, a0) DSB4(0, 0, b) DSB4(0, 1, c) DSA4(0, 1, a1)
        SGA0(1);
        PH2(); MMQ5(0, 0, a0, b) PH_END();
        SGA1(1);
        PH2(); MMQ5(0, 1, a0, c) PH_END();
        PH2(); MMQ5(1, 1, a1, c) PH_END();
        PH2(); MMQ5(1, 0, a1, b) PH_END_VM(0);
        DSA4(1, 0, a0) DSB4(1, 0, b) DSB4(1, 1, c) DSA4(1, 1, a1)
        PH2(); MMQ5(0, 0, a0, b) PH_END();
        PH2(); MMQ5(0, 1, a0, c) PH_END();
        PH2(); MMQ5(1, 1, a1, c) PH_END();
        PH2(); MMQ5(1, 0, a1, b)
        __builtin_amdgcn_s_setprio(0);
    }
#undef SGA0
#undef SGA1
#undef SGB0
#undef SGB1
}

// k1: h1[(b*C+c)][t] = yat(xT, twb); M=49152 N=384 K=224 (R9 core).
__global__ __launch_bounds__(256) void k1_token_yat(
    const u16* __restrict__ xT, const u16* __restrict__ twb,
    const float* __restrict__ tb, const float* __restrict__ twn,
    const float* __restrict__ xn1, const float* __restrict__ alpha, float sb,
    u16* __restrict__ h1) {
    const int m0 = (blockIdx.x + blockIdx.y * 8) * 128;
    const int n0 = blockIdx.z * 128;
    MFMA_CORE(xT + (size_t)m0 * PPAD, twb + (size_t)n0 * PPAD, PPAD, PPAD, PPAD / 32)
    float scale = powf(sqrtf(sb), alpha[0]);
    #pragma unroll
    for (int i = 0; i < 4; ++i) {
        #pragma unroll
        for (int j = 0; j < 4; ++j) {
            int col = cbase + j * 16 + l15;
            float bn = tb[col], wnn = twn[col];
            #pragma unroll
            for (int reg = 0; reg < 4; ++reg) {
                int row = rbase + i * 16 + quad * 4 + reg;
                float dnb = acc[i][j][reg];
                float dot = dnb + bn;
                float dist = wnn + xn1[row] - 2.f * dnb;
                float r = __builtin_amdgcn_rcpf(dist + EPSY);
                h1[(size_t)row * TM_ + col] = f2bf(scale * dot * dot * r);
            }
        }
    }
}

// k3: h3 = yat(x1b, cwb); M=12544 N=3072 K=768. 4-wave 8-phase 128² core.
// grid (8,13,24): mt = x + y*8 (XCD stripe, guard <98), n-tile = z.
__global__ __launch_bounds__(256, 2) void k3_chan_yat(
    const u16* __restrict__ x1b, const u16* __restrict__ cwb,
    const float* __restrict__ cb, const float* __restrict__ cwn,
    const float* __restrict__ xn2, const float* __restrict__ alpha, float sb,
    u16* __restrict__ h3) {
    __shared__ __align__(16) u16 smem[32768];
    const int mt = blockIdx.x + blockIdx.y * 8;
    if (mt >= (B_ * P_) / 128) return;
    const int m0 = mt * 128;
    const int n0 = blockIdx.z * 128;
    const int t = threadIdx.x;
    const int w = t >> 6, l = t & 63;
    const int wr = w >> 1, wc = w & 1;
    const int quad = l >> 4, l15 = l & 15;
    f32x4 acc[4][4];
    #pragma unroll
    for (int m = 0; m < 4; ++m)
        #pragma unroll
        for (int n = 0; n < 4; ++n) acc[m][n] = (f32x4){0.f, 0.f, 0.f, 0.f};
    mfma128_8p(x1b + (size_t)m0 * C_, cwb + (size_t)n0 * C_,
               C_, C_, C_ / 64, acc, smem);
    const int rbase = m0 + wr * 64;
    const int cbase = n0 + wc * 64;
    float scale = powf(sqrtf(sb), alpha[0]);
    #pragma unroll
    for (int m = 0; m < 4; ++m) {
        #pragma unroll
        for (int n = 0; n < 4; ++n) {
            int col = cbase + n * 16 + l15;
            float bn = cb[col], wnn = cwn[col];
            #pragma unroll
            for (int reg = 0; reg < 4; ++reg) {
                int row = rbase + m * 16 + quad * 4 + reg;
                float dnb = acc[m][n][reg];
                float dot = dnb + bn;
                float dist = wnn + xn2[row] - 2.f * dnb;
                float r = __builtin_amdgcn_rcpf(dist + EPSY);
                h3[(size_t)row * CM_ + col] = f2bf(scale * dot * dot * r);
            }
        }
    }
}

// k2: x1b = bf16(x + w2 . h1[b]^T + b2); fused xn2 row-norm atomics (R9 core).
__global__ __launch_bounds__(256) void k2_token_out(
    const u16* __restrict__ w2b, const u16* __restrict__ h1,
    const float* __restrict__ b2, const float* __restrict__ x,
    float* __restrict__ xn2, u16* __restrict__ x1b) {
    const int m0 = blockIdx.x * 128, n0 = blockIdx.y * 128;
    const u16* Bz = h1 + (size_t)blockIdx.z * C_ * TM_;
    MFMA_CORE(w2b + (size_t)m0 * TM_, Bz + (size_t)n0 * TM_, TM_, TM_, TM_ / 32)
    const float* rz = x + (size_t)blockIdx.z * P_ * C_;
    u16* oz = x1b + (size_t)blockIdx.z * P_ * C_;
    float* xrow = xn2 + (size_t)blockIdx.z * P_;
    #pragma unroll
    for (int i = 0; i < 4; ++i) {
        #pragma unroll
        for (int reg = 0; reg < 4; ++reg) {
            int row = rbase + i * 16 + quad * 4 + reg;
            if (row < P_) {
                float bm = b2[row];
                float s = 0.f;
                #pragma unroll
                for (int j = 0; j < 4; ++j) {
                    int col = cbase + j * 16 + l15;
                    float v = acc[i][j][reg] + bm + rz[(size_t)row * C_ + col];
                    u16 h = f2bf(v);
                    oz[(size_t)row * C_ + col] = h;
                    float vb = bf2f(h);
                    s = fmaf(vb, vb, s);
                }
                s += __shfl_xor(s, 1, 64);
                s += __shfl_xor(s, 2, 64);
                s += __shfl_xor(s, 4, 64);
                s += __shfl_xor(s, 8, 64);
                if (l15 == 0) atomicAdd(&xrow[row], s);
            }
        }
    }
}

// k4 split-K on the 4-wave 128² core: grid (8,13,6*nsplit):
// mt = x + y*8 (guard <98), n0 = (z%6)*128, ks = z/6.
__global__ __launch_bounds__(256, 2) void k4_split(
    const u16* __restrict__ h3, const u16* __restrict__ w4b,
    u16* __restrict__ pbuf, int KK) {
    __shared__ __align__(16) u16 smem[32768];
    const int mt = blockIdx.x + blockIdx.y * 8;
    if (mt >= (B_ * P_) / 128) return;
    const int m0 = mt * 128;
    const int nz = blockIdx.z;
    const int n0 = (nz % (C_ / 128)) * 128;
    const int ks = nz / (C_ / 128);
    const int kbase = ks * KK;
    const int t = threadIdx.x;
    const int w = t >> 6, l = t & 63;
    const int wr = w >> 1, wc = w & 1;
    const int quad = l >> 4, l15 = l & 15;
    f32x4 acc[4][4];
    #pragma unroll
    for (int m = 0; m < 4; ++m)
        #pragma unroll
        for (int n = 0; n < 4; ++n) acc[m][n] = (f32x4){0.f, 0.f, 0.f, 0.f};
    mfma128_8p(h3 + (size_t)m0 * CM_ + kbase, w4b + (size_t)n0 * CM_ + kbase,
               CM_, CM_, KK / 64, acc, smem);
    const int rbase = m0 + wr * 64;
    const int cbase = n0 + wc * 64;
    u16* dst = pbuf + (size_t)ks * ((size_t)B_ * P_ * C_);
    #pragma unroll
    for (int m = 0; m < 4; ++m) {
        #pragma unroll
        for (int n = 0; n < 4; ++n) {
            int col = cbase + n * 16 + l15;
            #pragma unroll
            for (int reg = 0; reg < 4; ++reg) {
                int row = rbase + m * 16 + quad * 4 + reg;
                dst[(size_t)row * C_ + col] = f2bf(acc[m][n][reg]);
            }
        }
    }
}

// reduce: out = sum(bf16 pbuf[0..NS-1]) + bf2f(x1b) + b4
template <int NS>
__global__ __launch_bounds__(256) void k4_reduce(
    float* __restrict__ outp, const u16* __restrict__ pbuf,
    const u16* __restrict__ x1b, const float* __restrict__ b4) {
    int idx = blockIdx.x * 256 + threadIdx.x;      // < B*P*C/4
    int c = (idx * 4) % C_;
    ushort4 r = ((const ushort4*)x1b)[idx];
    float4 o;
    o.x = bf2f(r.x) + b4[c + 0];
    o.y = bf2f(r.y) + b4[c + 1];
    o.z = bf2f(r.z) + b4[c + 2];
    o.w = bf2f(r.w) + b4[c + 3];
    const size_t stride4 = (size_t)B_ * P_ * C_ / 4;
    #pragma unroll
    for (int s = 0; s < NS; ++s) {
        ushort4 p = ((const ushort4*)pbuf)[idx + s * stride4];
        o.x += bf2f(p.x); o.y += bf2f(p.y); o.z += bf2f(p.z); o.w += bf2f(p.w);
    }
    ((float4*)outp)[idx] = o;
}

// fallback k4 (tiny ws): 128x64 tile BK=32
__global__ __launch_bounds__(256) void gemm_k4_fb(
    const u16* __restrict__ A, const u16* __restrict__ Bmat,
    const float* __restrict__ biasN, const u16* __restrict__ resB,
    float* __restrict__ Fout) {
    __shared__ u16 As[128 * 32];
    __shared__ u16 Bs[64 * 32];
    const int t = threadIdx.x;
    const int wid = t >> 6, lane = t & 63;
    const int quad = lane >> 4, l15 = lane & 15;
    const int m0 = blockIdx.x * 128, n0 = blockIdx.y * 64;
    f32x4 acc[4][2];
    #pragma unroll
    for (int i = 0; i < 4; ++i)
        #pragma unroll
        for (int j = 0; j < 2; ++j) acc[i][j] = (f32x4){0.f, 0.f, 0.f, 0.f};
    const u16* Aw = As + (wid >> 1) * (64 * 32);
    const u16* Bw = Bs + (wid & 1) * (32 * 32);
    const int arow = t >> 2, akc = (t & 3) * 8;
    for (int k0 = 0; k0 < CM_; k0 += 32) {
        gl_lds16(A + (size_t)(m0 + arow) * CM_ + k0 + akc,      As + wid * 512);
        gl_lds16(A + (size_t)(m0 + 64 + arow) * CM_ + k0 + akc, As + 2048 + wid * 512);
        gl_lds16(Bmat + (size_t)(n0 + arow) * CM_ + k0 + akc,   Bs + wid * 512);
        __syncthreads();
        bf16x8 af[4], bfr[2];
        #pragma unroll
        for (int i = 0; i < 4; ++i)
            af[i] = *(const bf16x8*)(Aw + ((i * 16 + l15) * 32 + quad * 8));
        #pragma unroll
        for (int j = 0; j < 2; ++j)
            bfr[j] = *(const bf16x8*)(Bw + ((j * 16 + l15) * 32 + quad * 8));
        #pragma unroll
        for (int i = 0; i < 4; ++i)
            #pragma unroll
            for (int j = 0; j < 2; ++j)
                acc[i][j] = __builtin_amdgcn_mfma_f32_16x16x32_bf16(af[i], bfr[j], acc[i][j], 0, 0, 0);
        __syncthreads();
    }
    const int rbase = m0 + (wid >> 1) * 64;
    const int cbase = n0 + (wid & 1) * 32;
    #pragma unroll
    for (int i = 0; i < 4; ++i) {
        #pragma unroll
        for (int j = 0; j < 2; ++j) {
            int col = cbase + j * 16 + l15;
            float bn = biasN[col];
            #pragma unroll
            for (int reg = 0; reg < 4; ++reg) {
                int row = rbase + i * 16 + quad * 4 + reg;
                float v = acc[i][j][reg] + bn + bf2f(resB[(size_t)row * C_ + col]);
                Fout[(size_t)row * C_ + col] = v;
            }
        }
    }
}

extern "C" void kernel_launch(void* const* d_in, const int* in_sizes, int n_in,
                              void* d_out, int out_size, void* d_ws, size_t ws_size,
                              hipStream_t stream) {
    const float* x  = (const float*)d_in[0];
    const float* tw = (const float*)d_in[1];
    const float* tb = (const float*)d_in[2];
    const float* ta = (const float*)d_in[3];
    const float* w2 = (const float*)d_in[4];
    const float* b2 = (const float*)d_in[5];
    const float* cw = (const float*)d_in[6];
    const float* cb = (const float*)d_in[7];
    const float* ca = (const float*)d_in[8];
    const float* w4 = (const float*)d_in[9];
    const float* b4 = (const float*)d_in[10];
    float* out = (float*)d_out;

    // ---- workspace layout (aliased) ----
    char* ws = (char*)d_ws;
    u16* h1 = (u16*)ws;                                    // B*C*TM (37.7 MB)
    u16* xT = (u16*)(ws + 37748736);                       // (B*C) x 224 (22 MB)
    u16* h3 = (u16*)ws;                                    // (B*P) x CM (77 MB)
    size_t off = 77070336;
    u16* x1b = (u16*)(ws + off); off += (size_t)B_ * P_ * C_ * 2;
    u16* twb = (u16*)(ws + off); off += (size_t)TM_ * PPAD * 2;
    u16* w2b = (u16*)(ws + off); off += (size_t)256 * TM_ * 2;
    u16* cwb = (u16*)(ws + off); off += (size_t)CM_ * C_ * 2;
    u16* w4b = (u16*)(ws + off); off += (size_t)C_ * CM_ * 2;
    float* xn1 = (float*)(ws + off); off += (size_t)B_ * C_ * 4;
    float* xn2 = (float*)(ws + off); off += (size_t)B_ * P_ * 4;
    float* twn = (float*)(ws + off); off += (size_t)TM_ * 4;
    float* cwn = (float*)(ws + off); off += (size_t)CM_ * 4;
    u16* pbuf = (u16*)(ws + off);                          // bf16 split-K partials
    const size_t psz = (size_t)B_ * P_ * C_ * 2;           // 19,267,584 per buffer

    int nsplit = 1;
    if (ws_size >= off + 4 * psz)      nsplit = 4;
    else if (ws_size >= off + 2 * psz) nsplit = 2;

    const float SBT = (float)TM_ / logf((float)TM_ + 1.0f);
    const float SBC = (float)CM_ / logf((float)CM_ + 1.0f);

    // ---- prep ----
    hipMemsetAsync(xn1, 0, (size_t)(B_ * C_ + B_ * P_) * 4, stream);
    k_prep_weights<<<3552, 256, 0, stream>>>(tw, twb, twn, cw, cwb, cwn,
                                             w2, w2b, w4, w4b);
    k_prep_xT<<<dim3(PPAD / 32, C_ / 32, B_), 256, 0, stream>>>(x, xT, xn1);

    // ---- k1: M=49152 N=384 K=224 ; R9 core, XCD-swizzled grid (8,48,3) ----
    k1_token_yat<<<dim3(8, 48, 3), 256, 0, stream>>>(
        xT, twb, tb, twn, xn1, ta, SBT, h1);

    // ---- k2: M=256 N=768 K=384, per-batch ; R9 core ----
    k2_token_out<<<dim3(2, C_ / 128, B_), 256, 0, stream>>>(
        w2b, h1, b2, x, xn2, x1b);

    // ---- k3: M=12544 N=3072 K=768 ; 4-wave 128² 8-phase, grid (8,13,24) ----
    k3_chan_yat<<<dim3(8, 13, 24), 256, 0, stream>>>(
        x1b, cwb, cb, cwn, xn2, ca, SBC, h3);

    // ---- k4: M=12544 N=768 K=3072, split-K bf16 partials, 8p core ----
    if (nsplit > 1) {
        k4_split<<<dim3(8, 13, (C_ / 128) * nsplit), 256, 0, stream>>>(
            h3, w4b, pbuf, CM_ / nsplit);
        int n4 = B_ * P_ * C_ / 4;
        if (nsplit == 4)
            k4_reduce<4><<<(n4 + 255) / 256, 256, 0, stream>>>(out, pbuf, x1b, b4);
        else
            k4_reduce<2><<<(n4 + 255) / 256, 256, 0, stream>>>(out, pbuf, x1b, b4);
    } else {
        gemm_k4_fb<<<dim3(B_ * P_ / 128, C_ / 64), 256, 0, stream>>>(
            h3, w4b, b4, x1b, out);
    }
}

// Round 11
// 360.254 us; speedup vs baseline: 1.0926x; 1.0083x over previous
//
#include <hip/hip_runtime.h>
#include <hip/hip_bf16.h>
#include <math.h>

// MixerBlock on MI355X — R18: 8-phase core merged to 4 phases/iter (32 MFMA
// per barrier region). R16 killed VALU addressing (null on MfmaUtil), R17
// killed exposed LDS latency (null) -> phase cost is barrier-rendezvous-bound
// (16 barriers/iter around 78cy MFMA regions). Merged ledger (re-derived):
// P0 {all buf0 reads; stage A(buf1); bar; MMQ(0,*)} P1 {stage B(buf0); bar;
// MMQ(1,*); vmcnt(4)+bar = publish buf1} P2/P3 mirrored. Outstanding <=12,
// publishes retire exactly the right 8 loads; WAR class identical to R17
// (HW-passed). k1/k2 keep the R9 2-deep core; swizzle/cursors from R16.
#define B_   64
#define P_   196
#define PPAD 224
#define C_   768
#define TM_  384
#define CM_  3072
#define EPSY 0.1f

typedef unsigned short u16;
typedef __attribute__((ext_vector_type(8))) short bf16x8;
typedef __attribute__((ext_vector_type(4))) float f32x4;

__device__ __forceinline__ float bf2f(u16 v) {
    return __uint_as_float(((unsigned int)v) << 16);
}
__device__ __forceinline__ u16 f2bf(float f) {
    unsigned int u = __float_as_uint(f);
    unsigned int rounding = 0x7FFFu + ((u >> 16) & 1u);
    return (u16)((u + rounding) >> 16);
}

__device__ __forceinline__ void gl_lds16(const u16* g, u16* l) {
    __builtin_amdgcn_global_load_lds(
        (const __attribute__((address_space(1))) unsigned int*)g,
        (__attribute__((address_space(3))) unsigned int*)l,
        16, 0, 0);
}

// ---------------- prep ----------------

__global__ __launch_bounds__(256) void k_prep_xT(const float* __restrict__ x,
                                                 u16* __restrict__ xT,
                                                 float* __restrict__ xn1) {
    __shared__ u16 tile[32][33];
    __shared__ float colsum[32];
    const int b = blockIdx.z, p0 = blockIdx.x * 32, c0 = blockIdx.y * 32;
    const int tx = threadIdx.x & 31, ty = threadIdx.x >> 5;
    if (threadIdx.x < 32) colsum[threadIdx.x] = 0.f;
    const float* xb = x + (size_t)b * P_ * C_;
    float s = 0.f;
    #pragma unroll
    for (int r = 0; r < 4; ++r) {
        int p = p0 + ty + r * 8;
        float v = (p < P_) ? xb[(size_t)p * C_ + c0 + tx] : 0.f;
        u16 h = f2bf(v);
        tile[ty + r * 8][tx] = h;
        float vb = bf2f(h);
        s = fmaf(vb, vb, s);
    }
    __syncthreads();
    u16* dst = xT + ((size_t)b * C_ + c0) * PPAD + p0;
    #pragma unroll
    for (int r = 0; r < 4; ++r) {
        int cl = ty + r * 8;
        dst[(size_t)cl * PPAD + tx] = tile[tx][cl];
    }
    atomicAdd(&colsum[tx], s);
    __syncthreads();
    if (threadIdx.x < 32)
        atomicAdd(&xn1[(size_t)b * C_ + c0 + threadIdx.x], colsum[threadIdx.x]);
}

__device__ __forceinline__ void pad_norm_body(const float* in, u16* outb, float* norm,
                                              int rows, int inlen, int outlen,
                                              int bid, int tid) {
    int wave = (bid * 256 + tid) >> 6;
    int lane = tid & 63;
    if (wave >= rows) return;
    const float* src = in + (size_t)wave * inlen;
    u16* dst = outb + (size_t)wave * outlen;
    float s = 0.f;
    for (int i = lane; i < outlen; i += 64) {
        float v = (i < inlen) ? src[i] : 0.f;
        u16 h = f2bf(v);
        dst[i] = h;
        float vv = bf2f(h);
        s = fmaf(vv, vv, s);
    }
    #pragma unroll
    for (int off = 32; off > 0; off >>= 1) s += __shfl_down(s, off, 64);
    if (lane == 0) norm[wave] = s;
}

__global__ __launch_bounds__(256) void k_prep_weights(
    const float* __restrict__ tw, u16* __restrict__ twb, float* __restrict__ twn,
    const float* __restrict__ cw, u16* __restrict__ cwb, float* __restrict__ cwn,
    const float* __restrict__ w2, u16* __restrict__ w2b,
    const float* __restrict__ w4, u16* __restrict__ w4b) {
    int bid = blockIdx.x, tid = threadIdx.x;
    if (bid < 96) {
        pad_norm_body(tw, twb, twn, TM_, P_, PPAD, bid, tid);
    } else if (bid < 864) {
        pad_norm_body(cw, cwb, cwn, CM_, C_, C_, bid - 96, tid);
    } else if (bid < 1248) {
        int idx = (bid - 864) * 256 + tid;
        int row = idx / TM_;
        w2b[idx] = (row < P_) ? f2bf(w2[(size_t)row * TM_ + (idx % TM_)]) : (u16)0;
    } else {
        int idx = (bid - 1248) * 256 + tid;
        float4 v = ((const float4*)w4)[idx];
        ushort4 o;
        o.x = f2bf(v.x); o.y = f2bf(v.y); o.z = f2bf(v.z); o.w = f2bf(v.w);
        ((ushort4*)w4b)[idx] = o;
    }
}

// ---------------- R9 128x128 core (k1/k2: short-K shapes) ----------------
__device__ __forceinline__ void mfma_mainloop(
    const u16* __restrict__ A, const u16* __restrict__ B,
    int lda, int ldb, int kiters,
    f32x4 (&acc)[4][4], u16* As, u16* Bs) {
    const int t = threadIdx.x;
    const int w = t >> 6, l = t & 63;
    const int quad = l >> 4, l15 = l & 15;
    const int row0 = t >> 2, kc = (t & 3) * 8;

    const u16* pa0 = A + (size_t)row0 * lda + kc;
    const u16* pa1 = A + (size_t)(64 + row0) * lda + kc;
    const u16* pb0 = B + (size_t)row0 * ldb + kc;
    const u16* pb1 = B + (size_t)(64 + row0) * ldb + kc;

    u16* ldsA0 = As + w * 512;
    u16* ldsA1 = As + 2048 + w * 512;
    u16* ldsB0 = Bs + w * 512;
    u16* ldsB1 = Bs + 2048 + w * 512;

#define STAGE_(bsel)                                \
    do {                                            \
        const int nb_ = (bsel) * 4096;              \
        gl_lds16(pa0, ldsA0 + nb_); pa0 += 32;      \
        gl_lds16(pa1, ldsA1 + nb_); pa1 += 32;      \
        gl_lds16(pb0, ldsB0 + nb_); pb0 += 32;      \
        gl_lds16(pb1, ldsB1 + nb_); pb1 += 32;      \
    } while (0)

    STAGE_(0);
    if (kiters > 1) {
        STAGE_(1);
        asm volatile("s_waitcnt vmcnt(4)" ::: "memory");
    } else {
        asm volatile("s_waitcnt vmcnt(0)" ::: "memory");
    }
    __builtin_amdgcn_s_barrier();

    int cur = 0;
    for (int it = 0; it < kiters; ++it) {
        const u16* Aw = As + cur * 4096 + (w >> 1) * 2048;
        const u16* Bw = Bs + cur * 4096 + (w & 1) * 2048;
        bf16x8 af[4], bfr[4];
        #pragma unroll
        for (int i = 0; i < 4; ++i)
            af[i] = *(const bf16x8*)(Aw + ((i * 16 + l15) * 32 + quad * 8));
        #pragma unroll
        for (int j = 0; j < 4; ++j)
            bfr[j] = *(const bf16x8*)(Bw + ((j * 16 + l15) * 32 + quad * 8));
        asm volatile("s_waitcnt lgkmcnt(0)" ::: "memory");
        __builtin_amdgcn_sched_barrier(0);
        __builtin_amdgcn_s_barrier();
        const bool more2 = (it + 2 < kiters);
        if (more2) { STAGE_(cur); }
        __builtin_amdgcn_s_setprio(1);
        #pragma unroll
        for (int i = 0; i < 4; ++i)
            #pragma unroll
            for (int j = 0; j < 4; ++j)
                acc[i][j] = __builtin_amdgcn_mfma_f32_16x16x32_bf16(af[i], bfr[j], acc[i][j], 0, 0, 0);
        __builtin_amdgcn_s_setprio(0);
        if (it + 1 < kiters) {
            if (more2) asm volatile("s_waitcnt vmcnt(4)" ::: "memory");
            else       asm volatile("s_waitcnt vmcnt(0)" ::: "memory");
            __builtin_amdgcn_s_barrier();
        }
        cur ^= 1;
    }
#undef STAGE_
}

#define MFMA_CORE(AP, BP, LDA, LDB, KITERS)                              \
    __shared__ u16 As[2 * 128 * 32];                                     \
    __shared__ u16 Bs[2 * 128 * 32];                                     \
    const int t = threadIdx.x;                                           \
    const int wid = t >> 6, lane = t & 63;                               \
    const int quad = lane >> 4, l15 = lane & 15;                         \
    f32x4 acc[4][4];                                                     \
    _Pragma("unroll")                                                    \
    for (int i = 0; i < 4; ++i)                                          \
        _Pragma("unroll")                                                \
        for (int j = 0; j < 4; ++j) acc[i][j] = (f32x4){0.f,0.f,0.f,0.f};\
    mfma_mainloop(AP, BP, LDA, LDB, KITERS, acc, As, Bs);                \
    const int rbase = m0 + (wid >> 1) * 64;                              \
    const int cbase = n0 + (wid & 1) * 64;

// ---------------- R18 4-wave 4-phase 128x128 core, BK=64 (k3/k4) ----------------
// LDS elems: A [2][128][64] at 0 (16384), B at 16384. 65536 B total.
// Swizzle: LDS[r][c] = G[r][c ^ ((r&7)<<3)]. Ledger: P0 {buf0 reads; stage
// A(buf1)} P1 {stage B(buf0); vmcnt(4) = publish buf1} P2 {buf1 reads; stage
// A(buf0)} P3 {stage B(buf1); vmcnt(4) = publish buf0}. 32 MFMA/phase.
#define PH2()  do { __builtin_amdgcn_sched_barrier(0);                    \
    __builtin_amdgcn_s_barrier();                                         \
    __builtin_amdgcn_sched_barrier(0);                                    \
    __builtin_amdgcn_s_setprio(1); } while (0)
#define PH_END()  do { __builtin_amdgcn_s_setprio(0);                     \
    __builtin_amdgcn_sched_barrier(0);                                    \
    __builtin_amdgcn_s_barrier(); } while (0)
#define PH_END_VM(n) do { __builtin_amdgcn_s_setprio(0);                  \
    asm volatile("s_waitcnt vmcnt(" #n ")" ::: "memory");                 \
    __builtin_amdgcn_sched_barrier(0);                                    \
    __builtin_amdgcn_s_barrier(); } while (0)

#define DSA4(d, mh, Ar)                                                   \
    _Pragma("unroll")                                                     \
    for (int mi = 0; mi < 2; ++mi) {                                      \
        Ar[mi][0] = *(const bf16x8*)(aB0 + (d) * 8192 + ((mh) * 2 + mi) * 1024); \
        Ar[mi][1] = *(const bf16x8*)(aB1 + (d) * 8192 + ((mh) * 2 + mi) * 1024); \
    }
#define DSB4(d, nh, Br)                                                   \
    _Pragma("unroll")                                                     \
    for (int ni = 0; ni < 2; ++ni) {                                      \
        Br[ni][0] = *(const bf16x8*)(bB0 + (d) * 8192 + ((nh) * 2 + ni) * 1024); \
        Br[ni][1] = *(const bf16x8*)(bB1 + (d) * 8192 + ((nh) * 2 + ni) * 1024); \
    }
#define MMQ5(mh, nh, Ar, Br)                                              \
    _Pragma("unroll")                                                     \
    for (int kk = 0; kk < 2; ++kk)                                        \
        _Pragma("unroll")                                                 \
        for (int mi = 0; mi < 2; ++mi)                                    \
            _Pragma("unroll")                                             \
            for (int ni = 0; ni < 2; ++ni)                                \
                acc[(mh) * 2 + mi][(nh) * 2 + ni] =                       \
                    __builtin_amdgcn_mfma_f32_16x16x32_bf16(              \
                        Ar[mi][kk], Br[ni][kk],                           \
                        acc[(mh) * 2 + mi][(nh) * 2 + ni], 0, 0, 0);

__device__ __forceinline__ void mfma128_8p(
    const u16* __restrict__ gA, const u16* __restrict__ gB,
    int lda, int ldb, int ntiles,
    f32x4 (&acc)[4][4], u16* smem) {
    const int t = threadIdx.x;
    const int w = t >> 6, lane = t & 63;
    const int wr = w >> 1, wc = w & 1;
    const int quad = lane >> 4, l15 = lane & 15;

    // staging: thread t covers elems t*8 and 2048+t*8 of each 64x64 unit
    const int srow = t >> 3;                          // 0..31
    const int scol = (((t & 7) ^ (srow & 7)) << 3);   // pre-swizzled source col

    // monotone unit cursors (each staged once per K-tile, in tile order)
    const size_t a32 = (size_t)32 * lda;
    const size_t b32 = (size_t)32 * ldb;
    const u16* cA0 = gA + (size_t)srow * lda + scol;          // A rows 0..63
    const u16* cA1 = gA + (size_t)(64 + srow) * lda + scol;   // A rows 64..127
    const u16* cB0 = gB + (size_t)srow * ldb + scol;
    const u16* cB1 = gB + (size_t)(64 + srow) * ldb + scol;

#define SGA0(d) do { u16* s_ = smem + (d) * 8192 + t * 8;                 \
    gl_lds16(cA0, s_); gl_lds16(cA0 + a32, s_ + 2048); cA0 += 64; } while (0)
#define SGA1(d) do { u16* s_ = smem + (d) * 8192 + 4096 + t * 8;          \
    gl_lds16(cA1, s_); gl_lds16(cA1 + a32, s_ + 2048); cA1 += 64; } while (0)
#define SGB0(d) do { u16* s_ = smem + 16384 + (d) * 8192 + t * 8;         \
    gl_lds16(cB0, s_); gl_lds16(cB0 + b32, s_ + 2048); cB0 += 64; } while (0)
#define SGB1(d) do { u16* s_ = smem + 16384 + (d) * 8192 + 4096 + t * 8;  \
    gl_lds16(cB1, s_); gl_lds16(cB1 + b32, s_ + 2048); cB1 += 64; } while (0)

    // reads: swizzled slot addressing
    const int q = (quad * 8) ^ ((l15 & 7) << 3);
    const u16* aB0 = smem + (wr * 64 + l15) * 64 + q;
    const u16* aB1 = smem + (wr * 64 + l15) * 64 + (q ^ 32);
    const u16* bB0 = smem + 16384 + (wc * 64 + l15) * 64 + q;
    const u16* bB1 = smem + 16384 + (wc * 64 + l15) * 64 + (q ^ 32);

    // prologue: T0 {A0,A1,B0,B1} -> buf0 ; T1 {B0,B1} -> buf1 (12 loads)
    SGA0(0); SGA1(0); SGB0(0); SGB1(0);
    SGB0(1); SGB1(1);
    asm volatile("s_waitcnt vmcnt(4)" ::: "memory");   // retire T0 (8 loads)
    __builtin_amdgcn_s_barrier();

    bf16x8 a0[2][2], a1[2][2], b[2][2], c[2][2];
    const int NI = ntiles >> 1;
    for (int i = 0; i < NI - 1; ++i) {
        // P0: buf0 published — issue ALL buf0 reads (a0, b, c, a1 order),
        // stage A(buf1); 32 MFMA mh=0.
        DSA4(0, 0, a0) DSB4(0, 0, b) DSB4(0, 1, c) DSA4(0, 1, a1)
        SGA0(1); SGA1(1);
        PH2(); MMQ5(0, 0, a0, b) MMQ5(0, 1, a0, c) PH_END();
        // P1: stage B(buf0) for tile 2i+2; 32 MFMA mh=1; publish buf1.
        SGB0(0); SGB1(0);
        PH2(); MMQ5(1, 1, a1, c) MMQ5(1, 0, a1, b) PH_END_VM(4);
        // P2: buf1 published — issue ALL buf1 reads, stage A(buf0).
        DSA4(1, 0, a0) DSB4(1, 0, b) DSB4(1, 1, c) DSA4(1, 1, a1)
        SGA0(0); SGA1(0);
        PH2(); MMQ5(0, 0, a0, b) MMQ5(0, 1, a0, c) PH_END();
        // P3: stage B(buf1) for tile 2i+3; 32 MFMA mh=1; publish buf0.
        SGB0(1); SGB1(1);
        PH2(); MMQ5(1, 1, a1, c) MMQ5(1, 0, a1, b) PH_END_VM(4);
    }
    // tail: buf0 = tile ntiles-2, buf1 = tile ntiles-1; stage only buf1.A
    {
        DSA4(0, 0, a0) DSB4(0, 0, b) DSB4(0, 1, c) DSA4(0, 1, a1)
        SGA0(1); SGA1(1);
        PH2(); MMQ5(0, 0, a0, b) MMQ5(0, 1, a0, c) PH_END();
        PH2(); MMQ5(1, 1, a1, c) MMQ5(1, 0, a1, b) PH_END_VM(0);
        DSA4(1, 0, a0) DSB4(1, 0, b) DSB4(1, 1, c) DSA4(1, 1, a1)
        PH2(); MMQ5(0, 0, a0, b) MMQ5(0, 1, a0, c) PH_END();
        PH2(); MMQ5(1, 1, a1, c) MMQ5(1, 0, a1, b)
        __builtin_amdgcn_s_setprio(0);
    }
#undef SGA0
#undef SGA1
#undef SGB0
#undef SGB1
}

// k1: h1[(b*C+c)][t] = yat(xT, twb); M=49152 N=384 K=224 (R9 core).
__global__ __launch_bounds__(256) void k1_token_yat(
    const u16* __restrict__ xT, const u16* __restrict__ twb,
    const float* __restrict__ tb, const float* __restrict__ twn,
    const float* __restrict__ xn1, const float* __restrict__ alpha, float sb,
    u16* __restrict__ h1) {
    const int m0 = (blockIdx.x + blockIdx.y * 8) * 128;
    const int n0 = blockIdx.z * 128;
    MFMA_CORE(xT + (size_t)m0 * PPAD, twb + (size_t)n0 * PPAD, PPAD, PPAD, PPAD / 32)
    float scale = powf(sqrtf(sb), alpha[0]);
    #pragma unroll
    for (int i = 0; i < 4; ++i) {
        #pragma unroll
        for (int j = 0; j < 4; ++j) {
            int col = cbase + j * 16 + l15;
            float bn = tb[col], wnn = twn[col];
            #pragma unroll
            for (int reg = 0; reg < 4; ++reg) {
                int row = rbase + i * 16 + quad * 4 + reg;
                float dnb = acc[i][j][reg];
                float dot = dnb + bn;
                float dist = wnn + xn1[row] - 2.f * dnb;
                float r = __builtin_amdgcn_rcpf(dist + EPSY);
                h1[(size_t)row * TM_ + col] = f2bf(scale * dot * dot * r);
            }
        }
    }
}

// k3: h3 = yat(x1b, cwb); M=12544 N=3072 K=768. 4-phase 128² core.
// grid (8,13,24): mt = x + y*8 (XCD stripe, guard <98), n-tile = z.
__global__ __launch_bounds__(256, 2) void k3_chan_yat(
    const u16* __restrict__ x1b, const u16* __restrict__ cwb,
    const float* __restrict__ cb, const float* __restrict__ cwn,
    const float* __restrict__ xn2, const float* __restrict__ alpha, float sb,
    u16* __restrict__ h3) {
    __shared__ __align__(16) u16 smem[32768];
    const int mt = blockIdx.x + blockIdx.y * 8;
    if (mt >= (B_ * P_) / 128) return;
    const int m0 = mt * 128;
    const int n0 = blockIdx.z * 128;
    const int t = threadIdx.x;
    const int w = t >> 6, l = t & 63;
    const int wr = w >> 1, wc = w & 1;
    const int quad = l >> 4, l15 = l & 15;
    f32x4 acc[4][4];
    #pragma unroll
    for (int m = 0; m < 4; ++m)
        #pragma unroll
        for (int n = 0; n < 4; ++n) acc[m][n] = (f32x4){0.f, 0.f, 0.f, 0.f};
    mfma128_8p(x1b + (size_t)m0 * C_, cwb + (size_t)n0 * C_,
               C_, C_, C_ / 64, acc, smem);
    const int rbase = m0 + wr * 64;
    const int cbase = n0 + wc * 64;
    float scale = powf(sqrtf(sb), alpha[0]);
    #pragma unroll
    for (int m = 0; m < 4; ++m) {
        #pragma unroll
        for (int n = 0; n < 4; ++n) {
            int col = cbase + n * 16 + l15;
            float bn = cb[col], wnn = cwn[col];
            #pragma unroll
            for (int reg = 0; reg < 4; ++reg) {
                int row = rbase + m * 16 + quad * 4 + reg;
                float dnb = acc[m][n][reg];
                float dot = dnb + bn;
                float dist = wnn + xn2[row] - 2.f * dnb;
                float r = __builtin_amdgcn_rcpf(dist + EPSY);
                h3[(size_t)row * CM_ + col] = f2bf(scale * dot * dot * r);
            }
        }
    }
}

// k2: x1b = bf16(x + w2 . h1[b]^T + b2); fused xn2 row-norm atomics (R9 core).
__global__ __launch_bounds__(256) void k2_token_out(
    const u16* __restrict__ w2b, const u16* __restrict__ h1,
    const float* __restrict__ b2, const float* __restrict__ x,
    float* __restrict__ xn2, u16* __restrict__ x1b) {
    const int m0 = blockIdx.x * 128, n0 = blockIdx.y * 128;
    const u16* Bz = h1 + (size_t)blockIdx.z * C_ * TM_;
    MFMA_CORE(w2b + (size_t)m0 * TM_, Bz + (size_t)n0 * TM_, TM_, TM_, TM_ / 32)
    const float* rz = x + (size_t)blockIdx.z * P_ * C_;
    u16* oz = x1b + (size_t)blockIdx.z * P_ * C_;
    float* xrow = xn2 + (size_t)blockIdx.z * P_;
    #pragma unroll
    for (int i = 0; i < 4; ++i) {
        #pragma unroll
        for (int reg = 0; reg < 4; ++reg) {
            int row = rbase + i * 16 + quad * 4 + reg;
            if (row < P_) {
                float bm = b2[row];
                float s = 0.f;
                #pragma unroll
                for (int j = 0; j < 4; ++j) {
                    int col = cbase + j * 16 + l15;
                    float v = acc[i][j][reg] + bm + rz[(size_t)row * C_ + col];
                    u16 h = f2bf(v);
                    oz[(size_t)row * C_ + col] = h;
                    float vb = bf2f(h);
                    s = fmaf(vb, vb, s);
                }
                s += __shfl_xor(s, 1, 64);
                s += __shfl_xor(s, 2, 64);
                s += __shfl_xor(s, 4, 64);
                s += __shfl_xor(s, 8, 64);
                if (l15 == 0) atomicAdd(&xrow[row], s);
            }
        }
    }
}

// k4 split-K on the 4-phase 128² core: grid (8,13,6*nsplit):
// mt = x + y*8 (guard <98), n0 = (z%6)*128, ks = z/6.
__global__ __launch_bounds__(256, 2) void k4_split(
    const u16* __restrict__ h3, const u16* __restrict__ w4b,
    u16* __restrict__ pbuf, int KK) {
    __shared__ __align__(16) u16 smem[32768];
    const int mt = blockIdx.x + blockIdx.y * 8;
    if (mt >= (B_ * P_) / 128) return;
    const int m0 = mt * 128;
    const int nz = blockIdx.z;
    const int n0 = (nz % (C_ / 128)) * 128;
    const int ks = nz / (C_ / 128);
    const int kbase = ks * KK;
    const int t = threadIdx.x;
    const int w = t >> 6, l = t & 63;
    const int wr = w >> 1, wc = w & 1;
    const int quad = l >> 4, l15 = l & 15;
    f32x4 acc[4][4];
    #pragma unroll
    for (int m = 0; m < 4; ++m)
        #pragma unroll
        for (int n = 0; n < 4; ++n) acc[m][n] = (f32x4){0.f, 0.f, 0.f, 0.f};
    mfma128_8p(h3 + (size_t)m0 * CM_ + kbase, w4b + (size_t)n0 * CM_ + kbase,
               CM_, CM_, KK / 64, acc, smem);
    const int rbase = m0 + wr * 64;
    const int cbase = n0 + wc * 64;
    u16* dst = pbuf + (size_t)ks * ((size_t)B_ * P_ * C_);
    #pragma unroll
    for (int m = 0; m < 4; ++m) {
        #pragma unroll
        for (int n = 0; n < 4; ++n) {
            int col = cbase + n * 16 + l15;
            #pragma unroll
            for (int reg = 0; reg < 4; ++reg) {
                int row = rbase + m * 16 + quad * 4 + reg;
                dst[(size_t)row * C_ + col] = f2bf(acc[m][n][reg]);
            }
        }
    }
}

// reduce: out = sum(bf16 pbuf[0..NS-1]) + bf2f(x1b) + b4
template <int NS>
__global__ __launch_bounds__(256) void k4_reduce(
    float* __restrict__ outp, const u16* __restrict__ pbuf,
    const u16* __restrict__ x1b, const float* __restrict__ b4) {
    int idx = blockIdx.x * 256 + threadIdx.x;      // < B*P*C/4
    int c = (idx * 4) % C_;
    ushort4 r = ((const ushort4*)x1b)[idx];
    float4 o;
    o.x = bf2f(r.x) + b4[c + 0];
    o.y = bf2f(r.y) + b4[c + 1];
    o.z = bf2f(r.z) + b4[c + 2];
    o.w = bf2f(r.w) + b4[c + 3];
    const size_t stride4 = (size_t)B_ * P_ * C_ / 4;
    #pragma unroll
    for (int s = 0; s < NS; ++s) {
        ushort4 p = ((const ushort4*)pbuf)[idx + s * stride4];
        o.x += bf2f(p.x); o.y += bf2f(p.y); o.z += bf2f(p.z); o.w += bf2f(p.w);
    }
    ((float4*)outp)[idx] = o;
}

// fallback k4 (tiny ws): 128x64 tile BK=32
__global__ __launch_bounds__(256) void gemm_k4_fb(
    const u16* __restrict__ A, const u16* __restrict__ Bmat,
    const float* __restrict__ biasN, const u16* __restrict__ resB,
    float* __restrict__ Fout) {
    __shared__ u16 As[128 * 32];
    __shared__ u16 Bs[64 * 32];
    const int t = threadIdx.x;
    const int wid = t >> 6, lane = t & 63;
    const int quad = lane >> 4, l15 = lane & 15;
    const int m0 = blockIdx.x * 128, n0 = blockIdx.y * 64;
    f32x4 acc[4][2];
    #pragma unroll
    for (int i = 0; i < 4; ++i)
        #pragma unroll
        for (int j = 0; j < 2; ++j) acc[i][j] = (f32x4){0.f, 0.f, 0.f, 0.f};
    const u16* Aw = As + (wid >> 1) * (64 * 32);
    const u16* Bw = Bs + (wid & 1) * (32 * 32);
    const int arow = t >> 2, akc = (t & 3) * 8;
    for (int k0 = 0; k0 < CM_; k0 += 32) {
        gl_lds16(A + (size_t)(m0 + arow) * CM_ + k0 + akc,      As + wid * 512);
        gl_lds16(A + (size_t)(m0 + 64 + arow) * CM_ + k0 + akc, As + 2048 + wid * 512);
        gl_lds16(Bmat + (size_t)(n0 + arow) * CM_ + k0 + akc,   Bs + wid * 512);
        __syncthreads();
        bf16x8 af[4], bfr[2];
        #pragma unroll
        for (int i = 0; i < 4; ++i)
            af[i] = *(const bf16x8*)(Aw + ((i * 16 + l15) * 32 + quad * 8));
        #pragma unroll
        for (int j = 0; j < 2; ++j)
            bfr[j] = *(const bf16x8*)(Bw + ((j * 16 + l15) * 32 + quad * 8));
        #pragma unroll
        for (int i = 0; i < 4; ++i)
            #pragma unroll
            for (int j = 0; j < 2; ++j)
                acc[i][j] = __builtin_amdgcn_mfma_f32_16x16x32_bf16(af[i], bfr[j], acc[i][j], 0, 0, 0);
        __syncthreads();
    }
    const int rbase = m0 + (wid >> 1) * 64;
    const int cbase = n0 + (wid & 1) * 32;
    #pragma unroll
    for (int i = 0; i < 4; ++i) {
        #pragma unroll
        for (int j = 0; j < 2; ++j) {
            int col = cbase + j * 16 + l15;
            float bn = biasN[col];
            #pragma unroll
            for (int reg = 0; reg < 4; ++reg) {
                int row = rbase + i * 16 + quad * 4 + reg;
                float v = acc[i][j][reg] + bn + bf2f(resB[(size_t)row * C_ + col]);
                Fout[(size_t)row * C_ + col] = v;
            }
        }
    }
}

extern "C" void kernel_launch(void* const* d_in, const int* in_sizes, int n_in,
                              void* d_out, int out_size, void* d_ws, size_t ws_size,
                              hipStream_t stream) {
    const float* x  = (const float*)d_in[0];
    const float* tw = (const float*)d_in[1];
    const float* tb = (const float*)d_in[2];
    const float* ta = (const float*)d_in[3];
    const float* w2 = (const float*)d_in[4];
    const float* b2 = (const float*)d_in[5];
    const float* cw = (const float*)d_in[6];
    const float* cb = (const float*)d_in[7];
    const float* ca = (const float*)d_in[8];
    const float* w4 = (const float*)d_in[9];
    const float* b4 = (const float*)d_in[10];
    float* out = (float*)d_out;

    // ---- workspace layout (aliased) ----
    char* ws = (char*)d_ws;
    u16* h1 = (u16*)ws;                                    // B*C*TM (37.7 MB)
    u16* xT = (u16*)(ws + 37748736);                       // (B*C) x 224 (22 MB)
    u16* h3 = (u16*)ws;                                    // (B*P) x CM (77 MB)
    size_t off = 77070336;
    u16* x1b = (u16*)(ws + off); off += (size_t)B_ * P_ * C_ * 2;
    u16* twb = (u16*)(ws + off); off += (size_t)TM_ * PPAD * 2;
    u16* w2b = (u16*)(ws + off); off += (size_t)256 * TM_ * 2;
    u16* cwb = (u16*)(ws + off); off += (size_t)CM_ * C_ * 2;
    u16* w4b = (u16*)(ws + off); off += (size_t)C_ * CM_ * 2;
    float* xn1 = (float*)(ws + off); off += (size_t)B_ * C_ * 4;
    float* xn2 = (float*)(ws + off); off += (size_t)B_ * P_ * 4;
    float* twn = (float*)(ws + off); off += (size_t)TM_ * 4;
    float* cwn = (float*)(ws + off); off += (size_t)CM_ * 4;
    u16* pbuf = (u16*)(ws + off);                          // bf16 split-K partials
    const size_t psz = (size_t)B_ * P_ * C_ * 2;           // 19,267,584 per buffer

    int nsplit = 1;
    if (ws_size >= off + 4 * psz)      nsplit = 4;
    else if (ws_size >= off + 2 * psz) nsplit = 2;

    const float SBT = (float)TM_ / logf((float)TM_ + 1.0f);
    const float SBC = (float)CM_ / logf((float)CM_ + 1.0f);

    // ---- prep ----
    hipMemsetAsync(xn1, 0, (size_t)(B_ * C_ + B_ * P_) * 4, stream);
    k_prep_weights<<<3552, 256, 0, stream>>>(tw, twb, twn, cw, cwb, cwn,
                                             w2, w2b, w4, w4b);
    k_prep_xT<<<dim3(PPAD / 32, C_ / 32, B_), 256, 0, stream>>>(x, xT, xn1);

    // ---- k1: M=49152 N=384 K=224 ; R9 core, XCD-swizzled grid (8,48,3) ----
    k1_token_yat<<<dim3(8, 48, 3), 256, 0, stream>>>(
        xT, twb, tb, twn, xn1, ta, SBT, h1);

    // ---- k2: M=256 N=768 K=384, per-batch ; R9 core ----
    k2_token_out<<<dim3(2, C_ / 128, B_), 256, 0, stream>>>(
        w2b, h1, b2, x, xn2, x1b);

    // ---- k3: M=12544 N=3072 K=768 ; 4-wave 128² 4-phase, grid (8,13,24) ----
    k3_chan_yat<<<dim3(8, 13, 24), 256, 0, stream>>>(
        x1b, cwb, cb, cwn, xn2, ca, SBC, h3);

    // ---- k4: M=12544 N=768 K=3072, split-K bf16 partials, 4-phase core ----
    if (nsplit > 1) {
        k4_split<<<dim3(8, 13, (C_ / 128) * nsplit), 256, 0, stream>>>(
            h3, w4b, pbuf, CM_ / nsplit);
        int n4 = B_ * P_ * C_ / 4;
        if (nsplit == 4)
            k4_reduce<4><<<(n4 + 255) / 256, 256, 0, stream>>>(out, pbuf, x1b, b4);
        else
            k4_reduce<2><<<(n4 + 255) / 256, 256, 0, stream>>>(out, pbuf, x1b, b4);
    } else {
        gemm_k4_fb<<<dim3(B_ * P_ / 128, C_ / 64), 256, 0, stream>>>(
            h3, w4b, b4, x1b, out);
    }
}